// Round 2
// baseline (2986.920 us; speedup 1.0000x reference)
//
#include <hip/hip_runtime.h>

#define N_ENT   100000
#define N_REL   500
#define DD      50
#define LD      52      // padded row stride: 52*4 = 208 B, 16B-aligned rows
#define N_EDGES 2000000

// ---------------------------------------------------------------------------
// Register-tiled small GEMM: Y{a,b,c}[m][j] = sum_k X[m][k]*W{a,b,c}[k][j] (+bd)
// Block = 256 threads, handles MT=20 rows. Thread (mp,jp) computes a 2x2 tile
// (rows 2mp..2mp+1, cols 2jp..2jp+1) for NMAT matrices simultaneously.
// X tile staged in LDS; W in LDS; float2 LDS reads. Outputs stride LD, pads=0.
// ---------------------------------------------------------------------------
template<int NMAT>
__global__ void ent_pre_tiled(const float* __restrict__ X, int ldX,
                              const float* __restrict__ Wa,
                              const float* __restrict__ Wb,
                              const float* __restrict__ Wc,
                              const float* __restrict__ bd,
                              float* __restrict__ Ya,
                              float* __restrict__ Yb,
                              float* __restrict__ Yc)
{
    constexpr int MT = 20;       // rows per block
    constexpr int MPAIRS = 10;   // 2-row pairs
    __shared__ float sW[NMAT][DD * DD];
    __shared__ float sX[MT * DD];

    for (int i = threadIdx.x; i < DD * DD; i += 256) {
        sW[0][i] = Wa[i];
        sW[1][i] = Wb[i];
        if (NMAT == 3) sW[2][i] = Wc[i];
    }
    const int m0 = blockIdx.x * MT;   // N_ENT % MT == 0
    for (int i = threadIdx.x; i < MT * DD; i += 256) {
        int row = i / DD, col = i - row * DD;
        sX[i] = X[(size_t)(m0 + row) * ldX + col];
    }
    __syncthreads();

    const int tid = threadIdx.x;
    if (tid >= MPAIRS * 25) return;
    const int mp = tid / 25, jp = tid - mp * 25;
    const int r0 = 2 * mp, j0 = 2 * jp;

    float acc[NMAT][2][2];
    #pragma unroll
    for (int t = 0; t < NMAT; t++)
        for (int i = 0; i < 2; i++)
            for (int c = 0; c < 2; c++) acc[t][i][c] = 0.f;
    if (NMAT == 3 && bd) {
        float b0 = bd[j0], b1 = bd[j0 + 1];
        acc[2][0][0] = b0; acc[2][0][1] = b1;
        acc[2][1][0] = b0; acc[2][1][1] = b1;
    }

    const float* xr0 = &sX[r0 * DD];
    const float* xr1 = &sX[r0 * DD + DD];
    for (int k = 0; k < DD; k++) {
        float x0 = xr0[k], x1 = xr1[k];
        #pragma unroll
        for (int t = 0; t < NMAT; t++) {
            float2 w = *(const float2*)&sW[t][k * DD + j0];
            acc[t][0][0] += x0 * w.x; acc[t][0][1] += x0 * w.y;
            acc[t][1][0] += x1 * w.x; acc[t][1][1] += x1 * w.y;
        }
    }

    float* const outs[3] = { Ya, Yb, (NMAT == 3) ? Yc : nullptr };
    #pragma unroll
    for (int t = 0; t < NMAT; t++) {
        float* Y = outs[t];
        #pragma unroll
        for (int i = 0; i < 2; i++) {
            size_t base = (size_t)(m0 + r0 + i) * LD;
            *(float2*)&Y[base + j0] = make_float2(acc[t][i][0], acc[t][i][1]);
            if (jp == 0) { Y[base + 50] = 0.f; Y[base + 51] = 0.f; }  // zero pads
        }
    }
}

// rel_out = (relu?) Rin @ Wr ; RW_out = Rin @ Wmid   (M = N_REL, tiny)
__global__ void rel_pre_kernel(const float* __restrict__ Rin, int ld_in,
                               const float* __restrict__ Wr,
                               const float* __restrict__ Wmid,
                               int do_relu,
                               float* __restrict__ rel_out, int ld_rel,
                               float* __restrict__ RW_out)
{
    __shared__ float sWr[DD * DD];
    __shared__ float sWm[DD * DD];
    for (int i = threadIdx.x; i < DD * DD; i += blockDim.x) {
        sWr[i] = Wr[i];
        sWm[i] = Wmid[i];
    }
    __syncthreads();
    int idx = blockIdx.x * blockDim.x + threadIdx.x;
    if (idx >= N_REL * DD) return;
    int m = idx / DD, j = idx - m * DD;
    const float* x = Rin + (size_t)m * ld_in;
    float ar = 0.f, am = 0.f;
    for (int k = 0; k < DD; k++) {
        float xv = x[k];
        ar += xv * sWr[k * DD + j];
        am += xv * sWm[k * DD + j];
    }
    if (do_relu) ar = fmaxf(ar, 0.f);
    rel_out[(size_t)m * ld_rel + j] = ar;
    RW_out[(size_t)m * LD + j] = am;
    if (j == 0) {
        RW_out[(size_t)m * LD + 50] = 0.f;
        RW_out[(size_t)m * LD + 51] = 0.f;
        if (ld_rel == LD) {
            rel_out[(size_t)m * LD + 50] = 0.f;
            rel_out[(size_t)m * LD + 51] = 0.f;
        }
    }
}

// ---------------------------------------------------------------------------
// CSR build
// ---------------------------------------------------------------------------
__global__ void hist_kernel(const int* __restrict__ h, int* __restrict__ counts, int nE)
{
    int e = blockIdx.x * blockDim.x + threadIdx.x;
    if (e < nE) atomicAdd(&counts[h[e]], 1);
}

__global__ void scan_kernel(const int* __restrict__ counts,
                            int* __restrict__ offs,
                            int* __restrict__ cursor, int nU)
{
    __shared__ int part[1024];
    int t = threadIdx.x;
    int chunk = (nU + 1023) / 1024;
    int b = t * chunk;
    int e = min(b + chunk, nU);
    int s = 0;
    for (int i = b; i < e; i++) s += counts[i];
    part[t] = s;
    __syncthreads();
    for (int off = 1; off < 1024; off <<= 1) {
        int v = (t >= off) ? part[t - off] : 0;
        __syncthreads();
        part[t] += v;
        __syncthreads();
    }
    int run = part[t] - s;
    for (int i = b; i < e; i++) {
        offs[i] = run;
        cursor[i] = run;
        run += counts[i];
    }
    if (b < nU && e == nU) offs[nU] = run;
}

__global__ void scatter_kernel(const int* __restrict__ h,
                               const int* __restrict__ r,
                               const int* __restrict__ t,
                               int* __restrict__ cursor,
                               int* __restrict__ hs,
                               int* __restrict__ rs,
                               int* __restrict__ ts, int nE)
{
    int e = blockIdx.x * blockDim.x + threadIdx.x;
    if (e >= nE) return;
    int u = h[e];
    int pos = atomicAdd(&cursor[u], 1);
    hs[pos] = u;
    rs[pos] = r[e];
    ts[pos] = t[e];
}

// ---------------------------------------------------------------------------
// Per-slot score with float4 gathers (rows are stride-LD, 16B-aligned)
// ---------------------------------------------------------------------------
__global__ void score_kernel(const int* __restrict__ hs,
                             const int* __restrict__ rs,
                             const int* __restrict__ ts,
                             const float* __restrict__ EW1,
                             const float* __restrict__ RW,
                             const float* __restrict__ EW3,
                             const float* __restrict__ a,
                             float* __restrict__ score, int nE)
{
    __shared__ float sa[LD];
    if (threadIdx.x < LD) sa[threadIdx.x] = (threadIdx.x < DD) ? a[threadIdx.x] : 0.f;
    __syncthreads();
    int e = blockIdx.x * blockDim.x + threadIdx.x;
    if (e >= nE) return;
    const float4* p1 = (const float4*)(EW1 + (size_t)hs[e] * LD);
    const float4* p2 = (const float4*)(RW  + (size_t)rs[e] * LD);
    const float4* p3 = (const float4*)(EW3 + (size_t)ts[e] * LD);
    float acc = 0.f;
    #pragma unroll
    for (int q = 0; q < 13; q++) {
        float4 v1 = p1[q], v2 = p2[q], v3 = p3[q];
        const float4 av = *(const float4*)&sa[4 * q];
        acc += (v1.x + v2.x + v3.x) * av.x
             + (v1.y + v2.y + v3.y) * av.y
             + (v1.z + v2.z + v3.z) * av.z
             + (v1.w + v2.w + v3.w) * av.w;
    }
    score[e] = acc >= 0.f ? acc : 0.2f * acc;
}

// ---------------------------------------------------------------------------
// Per-head softmax over contiguous slots (in place)
// ---------------------------------------------------------------------------
__global__ void softmax_kernel(const int* __restrict__ offs, float* __restrict__ score)
{
    int u = blockIdx.x * blockDim.x + threadIdx.x;
    if (u >= N_ENT) return;
    int s0 = offs[u], s1 = offs[u + 1];
    if (s0 >= s1) return;
    float m = -1e30f;
    for (int s = s0; s < s1; s++) m = fmaxf(m, score[s]);
    float sum = 0.f;
    for (int s = s0; s < s1; s++) {
        float ex = __expf(score[s] - m);
        score[s] = ex;
        sum += ex;
    }
    float inv = 1.f / (sum + 1e-9f);
    for (int s = s0; s < s1; s++) score[s] *= inv;
}

// ---------------------------------------------------------------------------
// Accumulate: thread per (u, j-quad). float4 gathers of RW/EW3 rows.
//   out[u][:] = (sum alpha)*EW1[u] + sum alpha*(RW[r]+EW3[t]) (+ base[u])
// full_ld != 0 -> output stride LD (float4 store incl pads); else stride DD.
// ---------------------------------------------------------------------------
__global__ void accum_kernel(const int* __restrict__ offs,
                             const int* __restrict__ rs,
                             const int* __restrict__ ts,
                             const float* __restrict__ alpha,
                             const float* __restrict__ EW1,
                             const float* __restrict__ RW,
                             const float* __restrict__ EW3,
                             const float* __restrict__ base,
                             float* __restrict__ outp, int full_ld)
{
    int idx = blockIdx.x * blockDim.x + threadIdx.x;
    if (idx >= N_ENT * 13) return;
    int u = idx / 13, q = idx - u * 13;
    int s0 = offs[u], s1 = offs[u + 1];
    float4 acc = make_float4(0.f, 0.f, 0.f, 0.f);
    float asum = 0.f;
    for (int s = s0; s < s1; s++) {
        float al = alpha[s];
        float4 vr = *(const float4*)(RW  + (size_t)rs[s] * LD + 4 * q);
        float4 vt = *(const float4*)(EW3 + (size_t)ts[s] * LD + 4 * q);
        asum += al;
        acc.x += al * (vr.x + vt.x);
        acc.y += al * (vr.y + vt.y);
        acc.z += al * (vr.z + vt.z);
        acc.w += al * (vr.w + vt.w);
    }
    float4 w1 = *(const float4*)(EW1 + (size_t)u * LD + 4 * q);
    acc.x += asum * w1.x; acc.y += asum * w1.y;
    acc.z += asum * w1.z; acc.w += asum * w1.w;
    if (base) {
        float4 b = *(const float4*)(base + (size_t)u * LD + 4 * q);
        acc.x += b.x; acc.y += b.y; acc.z += b.z; acc.w += b.w;
    }
    if (full_ld) {
        *(float4*)(outp + (size_t)u * LD + 4 * q) = acc;  // pads get 0 (all pad inputs 0)
    } else {
        int j0 = 4 * q;
        float v[4] = { acc.x, acc.y, acc.z, acc.w };
        #pragma unroll
        for (int c = 0; c < 4; c++)
            if (j0 + c < DD) outp[(size_t)u * DD + j0 + c] = v[c];
    }
}

// ---------------------------------------------------------------------------
extern "C" void kernel_launch(void* const* d_in, const int* in_sizes, int n_in,
                              void* d_out, int out_size, void* d_ws, size_t ws_size,
                              hipStream_t stream)
{
    const int*   h   = (const int*)d_in[0];
    const int*   r   = (const int*)d_in[1];
    const int*   t   = (const int*)d_in[2];
    const float* E   = (const float*)d_in[3];
    const float* R   = (const float*)d_in[4];
    const float* W0  = (const float*)d_in[5];
    const float* a0  = (const float*)d_in[6];
    const float* Wr0 = (const float*)d_in[7];
    const float* W1  = (const float*)d_in[8];
    const float* a1  = (const float*)d_in[9];
    const float* Wr1 = (const float*)d_in[10];
    const float* Wd  = (const float*)d_in[11];
    const float* bd  = (const float*)d_in[12];

    float* out_ent = (float*)d_out;                 // [N_ENT, DD] stride DD
    float* out_rel = out_ent + (size_t)N_ENT * DD;  // [N_REL, DD] stride DD

    // workspace layout (~116 MB)
    float* ws_f  = (float*)d_ws;
    float* EW1   = ws_f;                        // N_ENT*LD
    float* EW3   = EW1  + (size_t)N_ENT * LD;
    float* Ed    = EW3  + (size_t)N_ENT * LD;
    float* e0    = Ed   + (size_t)N_ENT * LD;
    float* RW    = e0   + (size_t)N_ENT * LD;   // N_REL*LD
    float* rel0  = RW   + (size_t)N_REL * LD;
    float* score = rel0 + (size_t)N_REL * LD;   // N_EDGES
    int* offs    = (int*)(score + N_EDGES);     // N_ENT+1
    int* hs      = offs + N_ENT + 1;            // N_EDGES
    int* rs      = hs + N_EDGES;
    int* ts      = rs + N_EDGES;
    // transient CSR-build buffers aliased into `score` (used before score pass)
    int* counts  = (int*)score;                 // N_ENT
    int* cursor  = counts + N_ENT;              // N_ENT

    const int BLK = 256;
    const int gE   = (N_EDGES + BLK - 1) / BLK;
    const int gU   = (N_ENT + BLK - 1) / BLK;
    const int gUQ  = (N_ENT * 13 + BLK - 1) / BLK;
    const int gRD  = (N_REL * DD + BLK - 1) / BLK;
    const int gPRE = N_ENT / 20;                // ent_pre_tiled: 20 rows/block

    // ---- CSR build (shared by both layers) ----
    hipMemsetAsync(counts, 0, (size_t)N_ENT * sizeof(int), stream);
    hist_kernel<<<gE, BLK, 0, stream>>>(h, counts, N_EDGES);
    scan_kernel<<<1, 1024, 0, stream>>>(counts, offs, cursor, N_ENT);
    scatter_kernel<<<gE, BLK, 0, stream>>>(h, r, t, cursor, hs, rs, ts, N_EDGES);

    // ---- layer 0 precompute ----
    rel_pre_kernel<<<gRD, BLK, 0, stream>>>(R, DD, Wr0, W0 + DD * DD, 1,
                                            rel0, LD, RW);
    ent_pre_tiled<3><<<gPRE, BLK, 0, stream>>>(E, DD, W0, W0 + 2 * DD * DD, Wd, bd,
                                               EW1, EW3, Ed);

    // ---- layer 0 attention ----
    score_kernel<<<gE, BLK, 0, stream>>>(hs, rs, ts, EW1, RW, EW3, a0, score, N_EDGES);
    softmax_kernel<<<gU, BLK, 0, stream>>>(offs, score);
    accum_kernel<<<gUQ, BLK, 0, stream>>>(offs, rs, ts, score, EW1, RW, EW3,
                                          nullptr, e0, 1);

    // ---- layer 1 precompute ----
    rel_pre_kernel<<<gRD, BLK, 0, stream>>>(rel0, LD, Wr1, W1 + DD * DD, 0,
                                            out_rel, DD, RW);
    ent_pre_tiled<2><<<gPRE, BLK, 0, stream>>>(e0, LD, W1, W1 + 2 * DD * DD,
                                               nullptr, nullptr, EW1, EW3, nullptr);

    // ---- layer 1 attention + fused residual ----
    score_kernel<<<gE, BLK, 0, stream>>>(hs, rs, ts, EW1, RW, EW3, a1, score, N_EDGES);
    softmax_kernel<<<gU, BLK, 0, stream>>>(offs, score);
    accum_kernel<<<gUQ, BLK, 0, stream>>>(offs, rs, ts, score, EW1, RW, EW3,
                                          Ed, out_ent, 0);
}

// Round 3
// 1325.747 us; speedup vs baseline: 2.2530x; 2.2530x over previous
//
#include <hip/hip_runtime.h>

#define N_ENT   100000
#define N_REL   500
#define DD      50
#define LD      52      // padded row stride: 52*4 = 208 B, 16B-aligned rows
#define N_EDGES 2000000

// ---------------------------------------------------------------------------
// Small GEMM, LDS-staged output: Y{a,b,c}[m][:] = X[m][:] @ W{a,b,c} (+bd)
// Block = 256 threads handles MT=20 rows. 250 threads compute 2x2 register
// tiles; results staged in sY[MT][LD] and flushed as one contiguous float4
// stream per matrix (full-line writes -> no partial-line RMW amplification).
// ---------------------------------------------------------------------------
template<int NMAT>
__global__ __launch_bounds__(256) void ent_pre_v3(
    const float* __restrict__ X, int ldX,
    const float* __restrict__ Wa,
    const float* __restrict__ Wb,
    const float* __restrict__ Wc,   // NMAT==3 only
    const float* __restrict__ bd,   // NMAT==3 only (bias on Yc)
    float* __restrict__ Ya,
    float* __restrict__ Yb,
    float* __restrict__ Yc)
{
    constexpr int MT = 20;       // rows per block; N_ENT % MT == 0
    __shared__ __align__(16) float sW[NMAT][DD * DD];
    __shared__ __align__(16) float sX[MT * LD];   // staged with runtime ldX
    __shared__ __align__(16) float sY[MT * LD];

    const int tid = threadIdx.x;

    // ---- stage W (float4; 2500 floats per matrix, 16B-aligned slices) ----
    for (int i = tid; i < DD * DD / 4; i += 256) {
        ((float4*)sW[0])[i] = ((const float4*)Wa)[i];
        ((float4*)sW[1])[i] = ((const float4*)Wb)[i];
        if (NMAT == 3) ((float4*)sW[2])[i] = ((const float4*)Wc)[i];
    }

    // ---- stage X tile: contiguous [m0*ldX, m0*ldX + MT*ldX) floats ----
    const int m0 = blockIdx.x * MT;
    const int nX4 = MT * ldX / 4;                 // 250 (ldX=50) or 260 (ldX=52)
    const float4* xsrc = (const float4*)(X + (size_t)m0 * ldX);
    for (int i = tid; i < nX4; i += 256) ((float4*)sX)[i] = xsrc[i];
    __syncthreads();

    // ---- compute: thread (mp,jp) -> rows 2mp,2mp+1, cols 2jp,2jp+1 ----
    const bool active = (tid < 250);
    const int mp = active ? tid / 25 : 0;
    const int jp = active ? tid % 25 : 0;
    const int r0 = 2 * mp, r1 = 2 * mp + 1, j0 = 2 * jp;

    float acc[NMAT][2][2];
    #pragma unroll
    for (int t = 0; t < NMAT; t++)
        #pragma unroll
        for (int i = 0; i < 2; i++)
            #pragma unroll
            for (int c = 0; c < 2; c++) acc[t][i][c] = 0.f;

    if (active) {
        if (NMAT == 3) {
            float b0 = bd[j0], b1 = bd[j0 + 1];
            acc[2][0][0] = b0; acc[2][0][1] = b1;
            acc[2][1][0] = b0; acc[2][1][1] = b1;
        }
        const float* xr0 = &sX[r0 * ldX];
        const float* xr1 = &sX[r1 * ldX];
        for (int k = 0; k < DD; k++) {
            float x0 = xr0[k], x1 = xr1[k];
            #pragma unroll
            for (int t = 0; t < NMAT; t++) {
                float2 w = *(const float2*)&sW[t][k * DD + j0];
                acc[t][0][0] += x0 * w.x; acc[t][0][1] += x0 * w.y;
                acc[t][1][0] += x1 * w.x; acc[t][1][1] += x1 * w.y;
            }
        }
    }

    // ---- per matrix: stage into sY, flush contiguously as float4 ----
    #pragma unroll
    for (int t = 0; t < NMAT; t++) {
        if (t > 0) __syncthreads();   // flush of previous t done
        if (active) {
            sY[r0 * LD + j0]     = acc[t][0][0];
            sY[r0 * LD + j0 + 1] = acc[t][0][1];
            sY[r1 * LD + j0]     = acc[t][1][0];
            sY[r1 * LD + j0 + 1] = acc[t][1][1];
            if (jp == 0) {        // keep pads finite (read via float4, x0 or discarded)
                sY[r0 * LD + 50] = 0.f; sY[r0 * LD + 51] = 0.f;
                sY[r1 * LD + 50] = 0.f; sY[r1 * LD + 51] = 0.f;
            }
        }
        __syncthreads();
        float* Y = (t == 0) ? Ya : ((t == 1) ? Yb : Yc);
        float4* dst = (float4*)(Y + (size_t)m0 * LD);   // 16B-aligned, contiguous
        for (int i = tid; i < MT * LD / 4; i += 256) dst[i] = ((const float4*)sY)[i];
    }
}

// rel_out = (relu?) Rin @ Wr ; RW_out = Rin @ Wmid   (M = N_REL, tiny)
__global__ void rel_pre_kernel(const float* __restrict__ Rin, int ld_in,
                               const float* __restrict__ Wr,
                               const float* __restrict__ Wmid,
                               int do_relu,
                               float* __restrict__ rel_out, int ld_rel,
                               float* __restrict__ RW_out)
{
    __shared__ float sWr[DD * DD];
    __shared__ float sWm[DD * DD];
    for (int i = threadIdx.x; i < DD * DD; i += blockDim.x) {
        sWr[i] = Wr[i];
        sWm[i] = Wmid[i];
    }
    __syncthreads();
    int idx = blockIdx.x * blockDim.x + threadIdx.x;
    if (idx >= N_REL * DD) return;
    int m = idx / DD, j = idx - m * DD;
    const float* x = Rin + (size_t)m * ld_in;
    float ar = 0.f, am = 0.f;
    for (int k = 0; k < DD; k++) {
        float xv = x[k];
        ar += xv * sWr[k * DD + j];
        am += xv * sWm[k * DD + j];
    }
    if (do_relu) ar = fmaxf(ar, 0.f);
    rel_out[(size_t)m * ld_rel + j] = ar;
    RW_out[(size_t)m * LD + j] = am;
    if (j == 0) {
        RW_out[(size_t)m * LD + 50] = 0.f;
        RW_out[(size_t)m * LD + 51] = 0.f;
        if (ld_rel == LD) {
            rel_out[(size_t)m * LD + 50] = 0.f;
            rel_out[(size_t)m * LD + 51] = 0.f;
        }
    }
}

// ---------------------------------------------------------------------------
// CSR build
// ---------------------------------------------------------------------------
__global__ void hist_kernel(const int* __restrict__ h, int* __restrict__ counts, int nE)
{
    int e = blockIdx.x * blockDim.x + threadIdx.x;
    if (e < nE) atomicAdd(&counts[h[e]], 1);
}

__global__ void scan_kernel(const int* __restrict__ counts,
                            int* __restrict__ offs,
                            int* __restrict__ cursor, int nU)
{
    __shared__ int part[1024];
    int t = threadIdx.x;
    int chunk = (nU + 1023) / 1024;
    int b = t * chunk;
    int e = min(b + chunk, nU);
    int s = 0;
    for (int i = b; i < e; i++) s += counts[i];
    part[t] = s;
    __syncthreads();
    for (int off = 1; off < 1024; off <<= 1) {
        int v = (t >= off) ? part[t - off] : 0;
        __syncthreads();
        part[t] += v;
        __syncthreads();
    }
    int run = part[t] - s;
    for (int i = b; i < e; i++) {
        offs[i] = run;
        cursor[i] = run;
        run += counts[i];
    }
    if (b < nU && e == nU) offs[nU] = run;
}

__global__ void scatter_kernel(const int* __restrict__ h,
                               const int* __restrict__ r,
                               const int* __restrict__ t,
                               int* __restrict__ cursor,
                               int* __restrict__ hs,
                               int* __restrict__ rs,
                               int* __restrict__ ts, int nE)
{
    int e = blockIdx.x * blockDim.x + threadIdx.x;
    if (e >= nE) return;
    int u = h[e];
    int pos = atomicAdd(&cursor[u], 1);
    hs[pos] = u;
    rs[pos] = r[e];
    ts[pos] = t[e];
}

// ---------------------------------------------------------------------------
// Per-slot score with float4 gathers (rows are stride-LD, 16B-aligned)
// ---------------------------------------------------------------------------
__global__ void score_kernel(const int* __restrict__ hs,
                             const int* __restrict__ rs,
                             const int* __restrict__ ts,
                             const float* __restrict__ EW1,
                             const float* __restrict__ RW,
                             const float* __restrict__ EW3,
                             const float* __restrict__ a,
                             float* __restrict__ score, int nE)
{
    __shared__ float sa[LD];
    if (threadIdx.x < LD) sa[threadIdx.x] = (threadIdx.x < DD) ? a[threadIdx.x] : 0.f;
    __syncthreads();
    int e = blockIdx.x * blockDim.x + threadIdx.x;
    if (e >= nE) return;
    const float4* p1 = (const float4*)(EW1 + (size_t)hs[e] * LD);
    const float4* p2 = (const float4*)(RW  + (size_t)rs[e] * LD);
    const float4* p3 = (const float4*)(EW3 + (size_t)ts[e] * LD);
    float acc = 0.f;
    #pragma unroll
    for (int q = 0; q < 13; q++) {
        float4 v1 = p1[q], v2 = p2[q], v3 = p3[q];
        const float4 av = *(const float4*)&sa[4 * q];
        acc += (v1.x + v2.x + v3.x) * av.x
             + (v1.y + v2.y + v3.y) * av.y
             + (v1.z + v2.z + v3.z) * av.z
             + (v1.w + v2.w + v3.w) * av.w;
    }
    score[e] = acc >= 0.f ? acc : 0.2f * acc;
}

// ---------------------------------------------------------------------------
// Per-head softmax over contiguous slots (in place)
// ---------------------------------------------------------------------------
__global__ void softmax_kernel(const int* __restrict__ offs, float* __restrict__ score)
{
    int u = blockIdx.x * blockDim.x + threadIdx.x;
    if (u >= N_ENT) return;
    int s0 = offs[u], s1 = offs[u + 1];
    if (s0 >= s1) return;
    float m = -1e30f;
    for (int s = s0; s < s1; s++) m = fmaxf(m, score[s]);
    float sum = 0.f;
    for (int s = s0; s < s1; s++) {
        float ex = __expf(score[s] - m);
        score[s] = ex;
        sum += ex;
    }
    float inv = 1.f / (sum + 1e-9f);
    for (int s = s0; s < s1; s++) score[s] *= inv;
}

// ---------------------------------------------------------------------------
// Accumulate: thread per (u, j-quad). float4 gathers of RW/EW3 rows.
//   out[u][:] = (sum alpha)*EW1[u] + sum alpha*(RW[r]+EW3[t]) (+ base[u])
// full_ld != 0 -> output stride LD (float4 store incl pads); else stride DD.
// ---------------------------------------------------------------------------
__global__ void accum_kernel(const int* __restrict__ offs,
                             const int* __restrict__ rs,
                             const int* __restrict__ ts,
                             const float* __restrict__ alpha,
                             const float* __restrict__ EW1,
                             const float* __restrict__ RW,
                             const float* __restrict__ EW3,
                             const float* __restrict__ base,
                             float* __restrict__ outp, int full_ld)
{
    int idx = blockIdx.x * blockDim.x + threadIdx.x;
    if (idx >= N_ENT * 13) return;
    int u = idx / 13, q = idx - u * 13;
    int s0 = offs[u], s1 = offs[u + 1];
    float4 acc = make_float4(0.f, 0.f, 0.f, 0.f);
    float asum = 0.f;
    for (int s = s0; s < s1; s++) {
        float al = alpha[s];
        float4 vr = *(const float4*)(RW  + (size_t)rs[s] * LD + 4 * q);
        float4 vt = *(const float4*)(EW3 + (size_t)ts[s] * LD + 4 * q);
        asum += al;
        acc.x += al * (vr.x + vt.x);
        acc.y += al * (vr.y + vt.y);
        acc.z += al * (vr.z + vt.z);
        acc.w += al * (vr.w + vt.w);
    }
    float4 w1 = *(const float4*)(EW1 + (size_t)u * LD + 4 * q);
    acc.x += asum * w1.x; acc.y += asum * w1.y;
    acc.z += asum * w1.z; acc.w += asum * w1.w;
    if (base) {
        float4 b = *(const float4*)(base + (size_t)u * LD + 4 * q);
        acc.x += b.x; acc.y += b.y; acc.z += b.z; acc.w += b.w;
    }
    if (full_ld) {
        *(float4*)(outp + (size_t)u * LD + 4 * q) = acc;  // pad inputs finite
    } else {
        int j0 = 4 * q;
        float v[4] = { acc.x, acc.y, acc.z, acc.w };
        #pragma unroll
        for (int c = 0; c < 4; c++)
            if (j0 + c < DD) outp[(size_t)u * DD + j0 + c] = v[c];
    }
}

// ---------------------------------------------------------------------------
extern "C" void kernel_launch(void* const* d_in, const int* in_sizes, int n_in,
                              void* d_out, int out_size, void* d_ws, size_t ws_size,
                              hipStream_t stream)
{
    const int*   h   = (const int*)d_in[0];
    const int*   r   = (const int*)d_in[1];
    const int*   t   = (const int*)d_in[2];
    const float* E   = (const float*)d_in[3];
    const float* R   = (const float*)d_in[4];
    const float* W0  = (const float*)d_in[5];
    const float* a0  = (const float*)d_in[6];
    const float* Wr0 = (const float*)d_in[7];
    const float* W1  = (const float*)d_in[8];
    const float* a1  = (const float*)d_in[9];
    const float* Wr1 = (const float*)d_in[10];
    const float* Wd  = (const float*)d_in[11];
    const float* bd  = (const float*)d_in[12];

    float* out_ent = (float*)d_out;                 // [N_ENT, DD] stride DD
    float* out_rel = out_ent + (size_t)N_ENT * DD;  // [N_REL, DD] stride DD

    // workspace layout (~116 MB)
    float* ws_f  = (float*)d_ws;
    float* EW1   = ws_f;                        // N_ENT*LD
    float* EW3   = EW1  + (size_t)N_ENT * LD;
    float* Ed    = EW3  + (size_t)N_ENT * LD;
    float* e0    = Ed   + (size_t)N_ENT * LD;
    float* RW    = e0   + (size_t)N_ENT * LD;   // N_REL*LD
    float* rel0  = RW   + (size_t)N_REL * LD;
    float* score = rel0 + (size_t)N_REL * LD;   // N_EDGES
    int* offs    = (int*)(score + N_EDGES);     // N_ENT+1
    int* hs      = offs + N_ENT + 1;            // N_EDGES
    int* rs      = hs + N_EDGES;
    int* ts      = rs + N_EDGES;
    // transient CSR-build buffers aliased into `score` (used before score pass)
    int* counts  = (int*)score;                 // N_ENT
    int* cursor  = counts + N_ENT;              // N_ENT

    const int BLK = 256;
    const int gE   = (N_EDGES + BLK - 1) / BLK;
    const int gU   = (N_ENT + BLK - 1) / BLK;
    const int gUQ  = (N_ENT * 13 + BLK - 1) / BLK;
    const int gRD  = (N_REL * DD + BLK - 1) / BLK;
    const int gPRE = N_ENT / 20;                // ent_pre_v3: 20 rows/block

    // ---- CSR build (shared by both layers) ----
    hipMemsetAsync(counts, 0, (size_t)N_ENT * sizeof(int), stream);
    hist_kernel<<<gE, BLK, 0, stream>>>(h, counts, N_EDGES);
    scan_kernel<<<1, 1024, 0, stream>>>(counts, offs, cursor, N_ENT);
    scatter_kernel<<<gE, BLK, 0, stream>>>(h, r, t, cursor, hs, rs, ts, N_EDGES);

    // ---- layer 0 precompute ----
    rel_pre_kernel<<<gRD, BLK, 0, stream>>>(R, DD, Wr0, W0 + DD * DD, 1,
                                            rel0, LD, RW);
    ent_pre_v3<3><<<gPRE, BLK, 0, stream>>>(E, DD, W0, W0 + 2 * DD * DD, Wd, bd,
                                            EW1, EW3, Ed);

    // ---- layer 0 attention ----
    score_kernel<<<gE, BLK, 0, stream>>>(hs, rs, ts, EW1, RW, EW3, a0, score, N_EDGES);
    softmax_kernel<<<gU, BLK, 0, stream>>>(offs, score);
    accum_kernel<<<gUQ, BLK, 0, stream>>>(offs, rs, ts, score, EW1, RW, EW3,
                                          nullptr, e0, 1);

    // ---- layer 1 precompute ----
    rel_pre_kernel<<<gRD, BLK, 0, stream>>>(rel0, LD, Wr1, W1 + DD * DD, 0,
                                            out_rel, DD, RW);
    ent_pre_v3<2><<<gPRE, BLK, 0, stream>>>(e0, LD, W1, W1 + 2 * DD * DD,
                                            nullptr, nullptr, EW1, EW3, nullptr);

    // ---- layer 1 attention + fused residual ----
    score_kernel<<<gE, BLK, 0, stream>>>(hs, rs, ts, EW1, RW, EW3, a1, score, N_EDGES);
    softmax_kernel<<<gU, BLK, 0, stream>>>(offs, score);
    accum_kernel<<<gUQ, BLK, 0, stream>>>(offs, rs, ts, score, EW1, RW, EW3,
                                          Ed, out_ent, 0);
}

// Round 4
// 785.712 us; speedup vs baseline: 3.8015x; 1.6873x over previous
//
#include <hip/hip_runtime.h>

#define N_ENT   100000
#define N_REL   500
#define DD      50
#define LD      52      // stride for sequentially-read tables (EW1/Ed/e0): 208 B
#define LD2     64      // stride for randomly-gathered tables (EW3/RW): 256 B = 2 lines
#define N_EDGES 2000000

// ---------------------------------------------------------------------------
// Small GEMM, LDS-staged output + fused row-dot-a:
//   Ya[m][:] = X[m][:] @ Wa         (stride lda) ; shOut[m] = Ya[m][:50].a
//   Yb[m][:] = X[m][:] @ Wb         (stride ldb) ; stOut[m] = Yb[m][:50].a
//   Yc[m][:] = X[m][:] @ Wc + bd    (stride ldc)   [NMAT==3 only]
// Block=256 handles MT=20 rows; 250 threads compute 2x2 register tiles;
// output staged in sY and flushed as contiguous float4 (full-line writes).
// ---------------------------------------------------------------------------
template<int NMAT>
__global__ __launch_bounds__(256) void ent_pre_v4(
    const float* __restrict__ X, int ldX,
    const float* __restrict__ Wa,
    const float* __restrict__ Wb,
    const float* __restrict__ Wc,
    const float* __restrict__ bd,
    const float* __restrict__ avec,
    float* __restrict__ Ya, int lda,
    float* __restrict__ Yb, int ldb,
    float* __restrict__ Yc, int ldc,
    float* __restrict__ shOut,
    float* __restrict__ stOut)
{
    constexpr int MT = 20;       // rows per block; N_ENT % MT == 0
    __shared__ __align__(16) float sW[NMAT][DD * DD];
    __shared__ __align__(16) float sX[MT * 52];
    __shared__ __align__(16) float sY[MT * 64];
    __shared__ float sa[DD];

    const int tid = threadIdx.x;

    for (int i = tid; i < DD * DD / 4; i += 256) {
        ((float4*)sW[0])[i] = ((const float4*)Wa)[i];
        ((float4*)sW[1])[i] = ((const float4*)Wb)[i];
        if (NMAT == 3) ((float4*)sW[2])[i] = ((const float4*)Wc)[i];
    }
    if (tid < DD) sa[tid] = avec[tid];

    const int m0 = blockIdx.x * MT;
    const int nX4 = MT * ldX / 4;     // 250 (ldX=50) or 260 (ldX=52); both 16B-OK
    const float4* xsrc = (const float4*)(X + (size_t)m0 * ldX);
    for (int i = tid; i < nX4; i += 256) ((float4*)sX)[i] = xsrc[i];
    __syncthreads();

    const bool active = (tid < 250);
    const int mp = active ? tid / 25 : 0;
    const int jp = active ? tid % 25 : 0;
    const int r0 = 2 * mp, r1 = 2 * mp + 1, j0 = 2 * jp;

    float acc[NMAT][2][2];
    #pragma unroll
    for (int t = 0; t < NMAT; t++)
        #pragma unroll
        for (int i = 0; i < 2; i++)
            #pragma unroll
            for (int c = 0; c < 2; c++) acc[t][i][c] = 0.f;

    if (active) {
        if (NMAT == 3) {
            float b0 = bd[j0], b1 = bd[j0 + 1];
            acc[2][0][0] = b0; acc[2][0][1] = b1;
            acc[2][1][0] = b0; acc[2][1][1] = b1;
        }
        const float* xr0 = &sX[r0 * ldX];
        const float* xr1 = &sX[r1 * ldX];
        for (int k = 0; k < DD; k++) {
            float x0 = xr0[k], x1 = xr1[k];
            #pragma unroll
            for (int t = 0; t < NMAT; t++) {
                float2 w = *(const float2*)&sW[t][k * DD + j0];
                acc[t][0][0] += x0 * w.x; acc[t][0][1] += x0 * w.y;
                acc[t][1][0] += x1 * w.x; acc[t][1][1] += x1 * w.y;
            }
        }
    }

    #pragma unroll
    for (int t = 0; t < NMAT; t++) {
        if (t > 0) __syncthreads();   // previous flush/dot complete
        const int ldt = (t == 0) ? lda : ((t == 1) ? ldb : ldc);
        // zero pad columns [DD, ldt)
        const int pw = ldt - DD;
        for (int i = tid; i < MT * pw; i += 256)
            sY[(i / pw) * ldt + DD + (i % pw)] = 0.f;
        if (active) {
            sY[r0 * ldt + j0]     = acc[t][0][0];
            sY[r0 * ldt + j0 + 1] = acc[t][0][1];
            sY[r1 * ldt + j0]     = acc[t][1][0];
            sY[r1 * ldt + j0 + 1] = acc[t][1][1];
        }
        __syncthreads();
        float* Y = (t == 0) ? Ya : ((t == 1) ? Yb : Yc);
        float4* dst = (float4*)(Y + (size_t)m0 * ldt);   // contiguous, aligned
        for (int i = tid; i < MT * ldt / 4; i += 256) dst[i] = ((const float4*)sY)[i];
        float* dOut = (t == 0) ? shOut : ((t == 1) ? stOut : nullptr);
        if (dOut && tid < MT) {
            const float* row = &sY[tid * ldt];
            float d = 0.f;
            for (int k = 0; k < DD; k++) d += row[k] * sa[k];
            dOut[m0 + tid] = d;
        }
    }
}

// rel_out = (relu?) Rin @ Wr (stride ld_rel); RW_out = Rin @ Wmid (stride LD2)
__global__ void rel_pre_kernel(const float* __restrict__ Rin, int ld_in,
                               const float* __restrict__ Wr,
                               const float* __restrict__ Wmid,
                               int do_relu,
                               float* __restrict__ rel_out, int ld_rel,
                               float* __restrict__ RW_out)
{
    __shared__ float sWr[DD * DD];
    __shared__ float sWm[DD * DD];
    for (int i = threadIdx.x; i < DD * DD; i += blockDim.x) {
        sWr[i] = Wr[i];
        sWm[i] = Wmid[i];
    }
    __syncthreads();
    int idx = blockIdx.x * blockDim.x + threadIdx.x;
    if (idx >= N_REL * DD) return;
    int m = idx / DD, j = idx - m * DD;
    const float* x = Rin + (size_t)m * ld_in;
    float ar = 0.f, am = 0.f;
    for (int k = 0; k < DD; k++) {
        float xv = x[k];
        ar += xv * sWr[k * DD + j];
        am += xv * sWm[k * DD + j];
    }
    if (do_relu) ar = fmaxf(ar, 0.f);
    rel_out[(size_t)m * ld_rel + j] = ar;
    RW_out[(size_t)m * LD2 + j] = am;
    if (j < LD2 - DD) RW_out[(size_t)m * LD2 + DD + j] = 0.f;  // zero pads
}

// sr[m] = RW[m][:50] . a
__global__ void sr_kernel(const float* __restrict__ RW,
                          const float* __restrict__ avec,
                          float* __restrict__ sr)
{
    int m = blockIdx.x * blockDim.x + threadIdx.x;
    if (m >= N_REL) return;
    float d = 0.f;
    for (int k = 0; k < DD; k++) d += RW[(size_t)m * LD2 + k] * avec[k];
    sr[m] = d;
}

// ---------------------------------------------------------------------------
// CSR build: histogram -> per-wave base assignment (order-free) -> scatter
// ---------------------------------------------------------------------------
__global__ void hist_kernel(const int* __restrict__ h, int* __restrict__ counts, int nE)
{
    int e = blockIdx.x * blockDim.x + threadIdx.x;
    if (e < nE) atomicAdd(&counts[h[e]], 1);
}

// Segment bases need not be ordered by entity id, only disjoint:
// wave-prefix-sum of counts + one atomicAdd on a global cursor per wave.
__global__ void assign_kernel(const int* __restrict__ counts,
                              int* __restrict__ s0,
                              int* __restrict__ cursor,
                              int* __restrict__ total)
{
    int u = blockIdx.x * blockDim.x + threadIdx.x;
    int c = (u < N_ENT) ? counts[u] : 0;
    int lane = threadIdx.x & 63;
    int incl = c;
    #pragma unroll
    for (int off = 1; off < 64; off <<= 1) {
        int v = __shfl_up(incl, off);
        if (lane >= off) incl += v;
    }
    int wave_total = __shfl(incl, 63);
    int base = 0;
    if (lane == 63) base = atomicAdd(total, wave_total);
    base = __shfl(base, 63);
    if (u < N_ENT) {
        int b = base + incl - c;
        s0[u] = b;
        cursor[u] = b;
    }
}

__global__ void scatter_kernel(const int* __restrict__ h,
                               const int* __restrict__ r,
                               const int* __restrict__ t,
                               int* __restrict__ cursor,
                               int* __restrict__ rs,
                               int* __restrict__ ts, int nE)
{
    int e = blockIdx.x * blockDim.x + threadIdx.x;
    if (e >= nE) return;
    int u = h[e];
    int pos = atomicAdd(&cursor[u], 1);
    rs[pos] = r[e];
    ts[pos] = t[e];
}

// ---------------------------------------------------------------------------
// Fused score + softmax, head-parallel. Scores are scalar sums:
//   score = leaky(sh[u] + sr[r] + st[t]);  alpha = softmax over segment.
// ---------------------------------------------------------------------------
__global__ void score_softmax_kernel(const int* __restrict__ s0,
                                     const int* __restrict__ counts,
                                     const int* __restrict__ rs,
                                     const int* __restrict__ ts,
                                     const float* __restrict__ sh,
                                     const float* __restrict__ sr,
                                     const float* __restrict__ st,
                                     float* __restrict__ alpha)
{
    int u = blockIdx.x * blockDim.x + threadIdx.x;
    if (u >= N_ENT) return;
    int b = s0[u], c = counts[u];
    if (c <= 0) return;
    float shu = sh[u];
    float m = -1e30f;
    for (int i = 0; i < c; i++) {
        float sc = shu + sr[rs[b + i]] + st[ts[b + i]];
        sc = sc >= 0.f ? sc : 0.2f * sc;
        alpha[b + i] = sc;
        m = fmaxf(m, sc);
    }
    float sum = 0.f;
    for (int i = 0; i < c; i++) {
        float ex = __expf(alpha[b + i] - m);
        alpha[b + i] = ex;
        sum += ex;
    }
    float inv = 1.f / (sum + 1e-9f);
    for (int i = 0; i < c; i++) alpha[b + i] *= inv;
}

// ---------------------------------------------------------------------------
// Accumulate: thread per (u, j-quad). float4 gathers of RW/EW3 (stride LD2,
// 256 B rows = exactly 2 aligned cache lines).
//   out[u][:] = (sum alpha)*EW1[u] + sum alpha*(RW[r]+EW3[t]) (+ base[u])
// ---------------------------------------------------------------------------
__global__ void accum_kernel(const int* __restrict__ s0v,
                             const int* __restrict__ counts,
                             const int* __restrict__ rs,
                             const int* __restrict__ ts,
                             const float* __restrict__ alpha,
                             const float* __restrict__ EW1,
                             const float* __restrict__ RW,
                             const float* __restrict__ EW3,
                             const float* __restrict__ base,
                             float* __restrict__ outp, int full_ld)
{
    int idx = blockIdx.x * blockDim.x + threadIdx.x;
    if (idx >= N_ENT * 13) return;
    int u = idx / 13, q = idx - u * 13;
    int s0 = s0v[u], s1 = s0 + counts[u];
    float4 acc = make_float4(0.f, 0.f, 0.f, 0.f);
    float asum = 0.f;
    for (int s = s0; s < s1; s++) {
        float al = alpha[s];
        float4 vr = *(const float4*)(RW  + (size_t)rs[s] * LD2 + 4 * q);
        float4 vt = *(const float4*)(EW3 + (size_t)ts[s] * LD2 + 4 * q);
        asum += al;
        acc.x += al * (vr.x + vt.x);
        acc.y += al * (vr.y + vt.y);
        acc.z += al * (vr.z + vt.z);
        acc.w += al * (vr.w + vt.w);
    }
    float4 w1 = *(const float4*)(EW1 + (size_t)u * LD + 4 * q);
    acc.x += asum * w1.x; acc.y += asum * w1.y;
    acc.z += asum * w1.z; acc.w += asum * w1.w;
    if (base) {
        float4 b = *(const float4*)(base + (size_t)u * LD + 4 * q);
        acc.x += b.x; acc.y += b.y; acc.z += b.z; acc.w += b.w;
    }
    if (full_ld) {
        *(float4*)(outp + (size_t)u * LD + 4 * q) = acc;  // pads finite
    } else {
        int j0 = 4 * q;
        float v[4] = { acc.x, acc.y, acc.z, acc.w };
        #pragma unroll
        for (int c = 0; c < 4; c++)
            if (j0 + c < DD) outp[(size_t)u * DD + j0 + c] = v[c];
    }
}

// ---------------------------------------------------------------------------
extern "C" void kernel_launch(void* const* d_in, const int* in_sizes, int n_in,
                              void* d_out, int out_size, void* d_ws, size_t ws_size,
                              hipStream_t stream)
{
    const int*   h   = (const int*)d_in[0];
    const int*   r   = (const int*)d_in[1];
    const int*   t   = (const int*)d_in[2];
    const float* E   = (const float*)d_in[3];
    const float* R   = (const float*)d_in[4];
    const float* W0  = (const float*)d_in[5];
    const float* a0  = (const float*)d_in[6];
    const float* Wr0 = (const float*)d_in[7];
    const float* W1  = (const float*)d_in[8];
    const float* a1  = (const float*)d_in[9];
    const float* Wr1 = (const float*)d_in[10];
    const float* Wd  = (const float*)d_in[11];
    const float* bd  = (const float*)d_in[12];

    float* out_ent = (float*)d_out;                 // [N_ENT, DD] stride DD
    float* out_rel = out_ent + (size_t)N_ENT * DD;  // [N_REL, DD] stride DD

    // workspace layout (~114 MB)
    float* ws_f  = (float*)d_ws;
    float* EW1   = ws_f;                         // N_ENT*LD
    float* Ed    = EW1  + (size_t)N_ENT * LD;    // N_ENT*LD
    float* e0    = Ed   + (size_t)N_ENT * LD;    // N_ENT*LD
    float* EW3   = e0   + (size_t)N_ENT * LD;    // N_ENT*LD2
    float* RW    = EW3  + (size_t)N_ENT * LD2;   // N_REL*LD2
    float* rel0  = RW   + (size_t)N_REL * LD2;   // N_REL*LD
    float* sh    = rel0 + (size_t)N_REL * LD;    // N_ENT
    float* st    = sh   + N_ENT;                 // N_ENT
    float* sr    = st   + N_ENT;                 // N_REL
    float* alpha = sr   + N_REL;                 // N_EDGES
    int* counts  = (int*)(alpha + N_EDGES);      // N_ENT
    int* total   = counts + N_ENT;               // 1   (memset with counts)
    int* s0      = total + 1;                    // N_ENT
    int* cursor  = s0 + N_ENT;                   // N_ENT
    int* rs      = cursor + N_ENT;               // N_EDGES
    int* ts      = rs + N_EDGES;                 // N_EDGES

    const int BLK = 256;
    const int gE   = (N_EDGES + BLK - 1) / BLK;
    const int gU   = (N_ENT + BLK - 1) / BLK;
    const int gUQ  = (N_ENT * 13 + BLK - 1) / BLK;
    const int gRD  = (N_REL * DD + BLK - 1) / BLK;
    const int gPRE = N_ENT / 20;

    // ---- CSR build (shared by both layers) ----
    hipMemsetAsync(counts, 0, (size_t)(N_ENT + 1) * sizeof(int), stream);
    hist_kernel<<<gE, BLK, 0, stream>>>(h, counts, N_EDGES);
    assign_kernel<<<gU, BLK, 0, stream>>>(counts, s0, cursor, total);
    scatter_kernel<<<gE, BLK, 0, stream>>>(h, r, t, cursor, rs, ts, N_EDGES);

    // ---- layer 0 precompute ----
    rel_pre_kernel<<<gRD, BLK, 0, stream>>>(R, DD, Wr0, W0 + DD * DD, 1,
                                            rel0, LD, RW);
    sr_kernel<<<2, BLK, 0, stream>>>(RW, a0, sr);
    ent_pre_v4<3><<<gPRE, BLK, 0, stream>>>(E, DD, W0, W0 + 2 * DD * DD, Wd, bd, a0,
                                            EW1, LD, EW3, LD2, Ed, LD, sh, st);

    // ---- layer 0 attention ----
    score_softmax_kernel<<<gU, BLK, 0, stream>>>(s0, counts, rs, ts, sh, sr, st, alpha);
    accum_kernel<<<gUQ, BLK, 0, stream>>>(s0, counts, rs, ts, alpha,
                                          EW1, RW, EW3, nullptr, e0, 1);

    // ---- layer 1 precompute ----
    rel_pre_kernel<<<gRD, BLK, 0, stream>>>(rel0, LD, Wr1, W1 + DD * DD, 0,
                                            out_rel, DD, RW);
    sr_kernel<<<2, BLK, 0, stream>>>(RW, a1, sr);
    ent_pre_v4<2><<<gPRE, BLK, 0, stream>>>(e0, LD, W1, W1 + 2 * DD * DD,
                                            nullptr, nullptr, a1,
                                            EW1, LD, EW3, LD2, nullptr, LD, sh, st);

    // ---- layer 1 attention + fused residual ----
    score_softmax_kernel<<<gU, BLK, 0, stream>>>(s0, counts, rs, ts, sh, sr, st, alpha);
    accum_kernel<<<gUQ, BLK, 0, stream>>>(s0, counts, rs, ts, alpha,
                                          EW1, RW, EW3, Ed, out_ent, 0);
}

// Round 5
// 753.847 us; speedup vs baseline: 3.9622x; 1.0423x over previous
//
#include <hip/hip_runtime.h>

#define N_ENT   100000
#define N_REL   500
#define DD      50
#define LD      52      // stride for sequentially-read tables (EW1/Ed/e0): 208 B
#define LD2     64      // stride for randomly-gathered tables (EW3/RW): 256 B = 2 lines
#define N_EDGES 2000000

// ---------------------------------------------------------------------------
// Small GEMM, LDS-staged output + fused row-dot-a:
//   Ya[m][:] = X[m][:] @ Wa         (stride lda) ; shOut[m] = Ya[m][:50].a
//   Yb[m][:] = X[m][:] @ Wb         (stride ldb) ; stOut[m] = Yb[m][:50].a
//   Yc[m][:] = X[m][:] @ Wc + bd    (stride ldc)   [NMAT==3 only]
// ---------------------------------------------------------------------------
template<int NMAT>
__global__ __launch_bounds__(256) void ent_pre_v4(
    const float* __restrict__ X, int ldX,
    const float* __restrict__ Wa,
    const float* __restrict__ Wb,
    const float* __restrict__ Wc,
    const float* __restrict__ bd,
    const float* __restrict__ avec,
    float* __restrict__ Ya, int lda,
    float* __restrict__ Yb, int ldb,
    float* __restrict__ Yc, int ldc,
    float* __restrict__ shOut,
    float* __restrict__ stOut)
{
    constexpr int MT = 20;       // rows per block; N_ENT % MT == 0
    __shared__ __align__(16) float sW[NMAT][DD * DD];
    __shared__ __align__(16) float sX[MT * 52];
    __shared__ __align__(16) float sY[MT * 64];
    __shared__ float sa[DD];

    const int tid = threadIdx.x;

    for (int i = tid; i < DD * DD / 4; i += 256) {
        ((float4*)sW[0])[i] = ((const float4*)Wa)[i];
        ((float4*)sW[1])[i] = ((const float4*)Wb)[i];
        if (NMAT == 3) ((float4*)sW[2])[i] = ((const float4*)Wc)[i];
    }
    if (tid < DD) sa[tid] = avec[tid];

    const int m0 = blockIdx.x * MT;
    const int nX4 = MT * ldX / 4;
    const float4* xsrc = (const float4*)(X + (size_t)m0 * ldX);
    for (int i = tid; i < nX4; i += 256) ((float4*)sX)[i] = xsrc[i];
    __syncthreads();

    const bool active = (tid < 250);
    const int mp = active ? tid / 25 : 0;
    const int jp = active ? tid % 25 : 0;
    const int r0 = 2 * mp, r1 = 2 * mp + 1, j0 = 2 * jp;

    float acc[NMAT][2][2];
    #pragma unroll
    for (int t = 0; t < NMAT; t++)
        #pragma unroll
        for (int i = 0; i < 2; i++)
            #pragma unroll
            for (int c = 0; c < 2; c++) acc[t][i][c] = 0.f;

    if (active) {
        if (NMAT == 3) {
            float b0 = bd[j0], b1 = bd[j0 + 1];
            acc[2][0][0] = b0; acc[2][0][1] = b1;
            acc[2][1][0] = b0; acc[2][1][1] = b1;
        }
        const float* xr0 = &sX[r0 * ldX];
        const float* xr1 = &sX[r1 * ldX];
        for (int k = 0; k < DD; k++) {
            float x0 = xr0[k], x1 = xr1[k];
            #pragma unroll
            for (int t = 0; t < NMAT; t++) {
                float2 w = *(const float2*)&sW[t][k * DD + j0];
                acc[t][0][0] += x0 * w.x; acc[t][0][1] += x0 * w.y;
                acc[t][1][0] += x1 * w.x; acc[t][1][1] += x1 * w.y;
            }
        }
    }

    #pragma unroll
    for (int t = 0; t < NMAT; t++) {
        if (t > 0) __syncthreads();
        const int ldt = (t == 0) ? lda : ((t == 1) ? ldb : ldc);
        const int pw = ldt - DD;
        for (int i = tid; i < MT * pw; i += 256)
            sY[(i / pw) * ldt + DD + (i % pw)] = 0.f;
        if (active) {
            sY[r0 * ldt + j0]     = acc[t][0][0];
            sY[r0 * ldt + j0 + 1] = acc[t][0][1];
            sY[r1 * ldt + j0]     = acc[t][1][0];
            sY[r1 * ldt + j0 + 1] = acc[t][1][1];
        }
        __syncthreads();
        float* Y = (t == 0) ? Ya : ((t == 1) ? Yb : Yc);
        float4* dst = (float4*)(Y + (size_t)m0 * ldt);
        for (int i = tid; i < MT * ldt / 4; i += 256) dst[i] = ((const float4*)sY)[i];
        float* dOut = (t == 0) ? shOut : ((t == 1) ? stOut : nullptr);
        if (dOut && tid < MT) {
            const float* row = &sY[tid * ldt];
            float d = 0.f;
            for (int k = 0; k < DD; k++) d += row[k] * sa[k];
            dOut[m0 + tid] = d;
        }
    }
}

// rel_out = (relu?) Rin @ Wr (stride ld_rel); RW_out = Rin @ Wmid (stride LD2)
__global__ void rel_pre_kernel(const float* __restrict__ Rin, int ld_in,
                               const float* __restrict__ Wr,
                               const float* __restrict__ Wmid,
                               int do_relu,
                               float* __restrict__ rel_out, int ld_rel,
                               float* __restrict__ RW_out)
{
    __shared__ float sWr[DD * DD];
    __shared__ float sWm[DD * DD];
    for (int i = threadIdx.x; i < DD * DD; i += blockDim.x) {
        sWr[i] = Wr[i];
        sWm[i] = Wmid[i];
    }
    __syncthreads();
    int idx = blockIdx.x * blockDim.x + threadIdx.x;
    if (idx >= N_REL * DD) return;
    int m = idx / DD, j = idx - m * DD;
    const float* x = Rin + (size_t)m * ld_in;
    float ar = 0.f, am = 0.f;
    for (int k = 0; k < DD; k++) {
        float xv = x[k];
        ar += xv * sWr[k * DD + j];
        am += xv * sWm[k * DD + j];
    }
    if (do_relu) ar = fmaxf(ar, 0.f);
    rel_out[(size_t)m * ld_rel + j] = ar;
    RW_out[(size_t)m * LD2 + j] = am;
    if (j < LD2 - DD) RW_out[(size_t)m * LD2 + DD + j] = 0.f;
}

// sr[m] = RW[m][:50] . a
__global__ void sr_kernel(const float* __restrict__ RW,
                          const float* __restrict__ avec,
                          float* __restrict__ sr)
{
    int m = blockIdx.x * blockDim.x + threadIdx.x;
    if (m >= N_REL) return;
    float d = 0.f;
    for (int k = 0; k < DD; k++) d += RW[(size_t)m * LD2 + k] * avec[k];
    sr[m] = d;
}

// ---------------------------------------------------------------------------
// CSR build: histogram -> per-wave base assignment (order-free) -> scatter
// ---------------------------------------------------------------------------
__global__ void hist_kernel(const int* __restrict__ h, int* __restrict__ counts, int nE)
{
    int e = blockIdx.x * blockDim.x + threadIdx.x;
    if (e < nE) atomicAdd(&counts[h[e]], 1);
}

__global__ void assign_kernel(const int* __restrict__ counts,
                              int* __restrict__ s0,
                              int* __restrict__ cursor,
                              int* __restrict__ total)
{
    int u = blockIdx.x * blockDim.x + threadIdx.x;
    int c = (u < N_ENT) ? counts[u] : 0;
    int lane = threadIdx.x & 63;
    int incl = c;
    #pragma unroll
    for (int off = 1; off < 64; off <<= 1) {
        int v = __shfl_up(incl, off);
        if (lane >= off) incl += v;
    }
    int wave_total = __shfl(incl, 63);
    int base = 0;
    if (lane == 63) base = atomicAdd(total, wave_total);
    base = __shfl(base, 63);
    if (u < N_ENT) {
        int b = base + incl - c;
        s0[u] = b;
        cursor[u] = b;
    }
}

// One 8 B packed store per edge (halves dirty-line count vs two 4 B streams)
__global__ void scatter_kernel(const int* __restrict__ h,
                               const int* __restrict__ r,
                               const int* __restrict__ t,
                               int* __restrict__ cursor,
                               int2* __restrict__ rt, int nE)
{
    int e = blockIdx.x * blockDim.x + threadIdx.x;
    if (e >= nE) return;
    int u = h[e];
    int pos = atomicAdd(&cursor[u], 1);
    rt[pos] = make_int2(r[e], t[e]);
}

// ---------------------------------------------------------------------------
// Unnormalized attention weights, head-parallel (1 pass):
//   ex = exp(leaky(sh[u] + sr[r] + st[t]))    (scores tiny -> no max needed)
// Normalization folded into accum's final divide.
// ---------------------------------------------------------------------------
__global__ void score_exp_kernel(const int* __restrict__ s0,
                                 const int* __restrict__ counts,
                                 const int2* __restrict__ rt,
                                 const float* __restrict__ sh,
                                 const float* __restrict__ sr,
                                 const float* __restrict__ st,
                                 float* __restrict__ ex)
{
    int u = blockIdx.x * blockDim.x + threadIdx.x;
    if (u >= N_ENT) return;
    int b = s0[u], c = counts[u];
    float shu = sh[u];
    for (int i = 0; i < c; i++) {
        int2 p = rt[b + i];
        float sc = shu + sr[p.x] + st[p.y];
        sc = sc >= 0.f ? sc : 0.2f * sc;
        ex[b + i] = __expf(sc);
    }
}

// ---------------------------------------------------------------------------
// Accumulate: thread per (u, j-quad):
//   out[u] = EW1[u] + (sum ex*(RW[r]+EW3[t])) / (sum ex)   (+ base[u])
//   empty segment -> 0 (+ base)
// ---------------------------------------------------------------------------
__global__ void accum_kernel(const int* __restrict__ s0v,
                             const int* __restrict__ counts,
                             const int2* __restrict__ rt,
                             const float* __restrict__ ex,
                             const float* __restrict__ EW1,
                             const float* __restrict__ RW,
                             const float* __restrict__ EW3,
                             const float* __restrict__ base,
                             float* __restrict__ outp, int full_ld)
{
    int idx = blockIdx.x * blockDim.x + threadIdx.x;
    if (idx >= N_ENT * 13) return;
    int u = idx / 13, q = idx - u * 13;
    int s0 = s0v[u], s1 = s0 + counts[u];
    float4 acc = make_float4(0.f, 0.f, 0.f, 0.f);
    float asum = 0.f;
    for (int s = s0; s < s1; s++) {
        float al = ex[s];
        int2 p = rt[s];
        float4 vr = *(const float4*)(RW  + (size_t)p.x * LD2 + 4 * q);
        float4 vt = *(const float4*)(EW3 + (size_t)p.y * LD2 + 4 * q);
        asum += al;
        acc.x += al * (vr.x + vt.x);
        acc.y += al * (vr.y + vt.y);
        acc.z += al * (vr.z + vt.z);
        acc.w += al * (vr.w + vt.w);
    }
    if (asum > 0.f) {
        float inv = 1.f / asum;
        float4 w1 = *(const float4*)(EW1 + (size_t)u * LD + 4 * q);
        acc.x = w1.x + acc.x * inv;
        acc.y = w1.y + acc.y * inv;
        acc.z = w1.z + acc.z * inv;
        acc.w = w1.w + acc.w * inv;
    }  // else: empty segment -> 0, matching ref
    if (base) {
        float4 b = *(const float4*)(base + (size_t)u * LD + 4 * q);
        acc.x += b.x; acc.y += b.y; acc.z += b.z; acc.w += b.w;
    }
    if (full_ld) {
        *(float4*)(outp + (size_t)u * LD + 4 * q) = acc;
    } else {
        int j0 = 4 * q;
        float v[4] = { acc.x, acc.y, acc.z, acc.w };
        #pragma unroll
        for (int c = 0; c < 4; c++)
            if (j0 + c < DD) outp[(size_t)u * DD + j0 + c] = v[c];
    }
}

// ---------------------------------------------------------------------------
extern "C" void kernel_launch(void* const* d_in, const int* in_sizes, int n_in,
                              void* d_out, int out_size, void* d_ws, size_t ws_size,
                              hipStream_t stream)
{
    const int*   h   = (const int*)d_in[0];
    const int*   r   = (const int*)d_in[1];
    const int*   t   = (const int*)d_in[2];
    const float* E   = (const float*)d_in[3];
    const float* R   = (const float*)d_in[4];
    const float* W0  = (const float*)d_in[5];
    const float* a0  = (const float*)d_in[6];
    const float* Wr0 = (const float*)d_in[7];
    const float* W1  = (const float*)d_in[8];
    const float* a1  = (const float*)d_in[9];
    const float* Wr1 = (const float*)d_in[10];
    const float* Wd  = (const float*)d_in[11];
    const float* bd  = (const float*)d_in[12];

    float* out_ent = (float*)d_out;                 // [N_ENT, DD] stride DD
    float* out_rel = out_ent + (size_t)N_ENT * DD;  // [N_REL, DD] stride DD

    // workspace layout (~114 MB)
    float* ws_f  = (float*)d_ws;
    float* EW1   = ws_f;                         // N_ENT*LD
    float* Ed    = EW1  + (size_t)N_ENT * LD;    // N_ENT*LD
    float* e0    = Ed   + (size_t)N_ENT * LD;    // N_ENT*LD
    float* EW3   = e0   + (size_t)N_ENT * LD;    // N_ENT*LD2
    float* RW    = EW3  + (size_t)N_ENT * LD2;   // N_REL*LD2
    float* rel0  = RW   + (size_t)N_REL * LD2;   // N_REL*LD
    float* sh    = rel0 + (size_t)N_REL * LD;    // N_ENT
    float* st    = sh   + N_ENT;                 // N_ENT
    float* sr    = st   + N_ENT;                 // N_REL
    float* exv   = sr   + N_REL;                 // N_EDGES
    int* counts  = (int*)(exv + N_EDGES);        // N_ENT
    int* total   = counts + N_ENT;               // 1 (memset with counts)
    int* s0      = total + 1;                    // N_ENT
    int* cursor  = s0 + N_ENT;                   // N_ENT
    int2* rt     = (int2*)(cursor + N_ENT);      // N_EDGES int2 (8B-aligned: offset even)

    const int BLK = 256;
    const int gE   = (N_EDGES + BLK - 1) / BLK;
    const int gU   = (N_ENT + BLK - 1) / BLK;
    const int gUQ  = (N_ENT * 13 + BLK - 1) / BLK;
    const int gRD  = (N_REL * DD + BLK - 1) / BLK;
    const int gPRE = N_ENT / 20;

    // ---- CSR build (shared by both layers) ----
    hipMemsetAsync(counts, 0, (size_t)(N_ENT + 1) * sizeof(int), stream);
    hist_kernel<<<gE, BLK, 0, stream>>>(h, counts, N_EDGES);
    assign_kernel<<<gU, BLK, 0, stream>>>(counts, s0, cursor, total);
    scatter_kernel<<<gE, BLK, 0, stream>>>(h, r, t, cursor, rt, N_EDGES);

    // ---- layer 0 precompute ----
    rel_pre_kernel<<<gRD, BLK, 0, stream>>>(R, DD, Wr0, W0 + DD * DD, 1,
                                            rel0, LD, RW);
    sr_kernel<<<2, BLK, 0, stream>>>(RW, a0, sr);
    ent_pre_v4<3><<<gPRE, BLK, 0, stream>>>(E, DD, W0, W0 + 2 * DD * DD, Wd, bd, a0,
                                            EW1, LD, EW3, LD2, Ed, LD, sh, st);

    // ---- layer 0 attention ----
    score_exp_kernel<<<gU, BLK, 0, stream>>>(s0, counts, rt, sh, sr, st, exv);
    accum_kernel<<<gUQ, BLK, 0, stream>>>(s0, counts, rt, exv,
                                          EW1, RW, EW3, nullptr, e0, 1);

    // ---- layer 1 precompute ----
    rel_pre_kernel<<<gRD, BLK, 0, stream>>>(rel0, LD, Wr1, W1 + DD * DD, 0,
                                            out_rel, DD, RW);
    sr_kernel<<<2, BLK, 0, stream>>>(RW, a1, sr);
    ent_pre_v4<2><<<gPRE, BLK, 0, stream>>>(e0, LD, W1, W1 + 2 * DD * DD,
                                            nullptr, nullptr, a1,
                                            EW1, LD, EW3, LD2, nullptr, LD, sh, st);

    // ---- layer 1 attention + fused residual ----
    score_exp_kernel<<<gU, BLK, 0, stream>>>(s0, counts, rt, sh, sr, st, exv);
    accum_kernel<<<gUQ, BLK, 0, stream>>>(s0, counts, rt, exv,
                                          EW1, RW, EW3, Ed, out_ent, 0);
}

// Round 6
// 701.071 us; speedup vs baseline: 4.2605x; 1.0753x over previous
//
#include <hip/hip_runtime.h>

#define N_ENT   100000
#define N_REL   500
#define DD      50
#define LD      52      // stride for sequentially-read tables (EW1/Ed/e0): 208 B
#define LD2     64      // stride for randomly-gathered tables (EW3/RW): 256 B = 2 lines
#define N_EDGES 2000000
#define T_BITS  17
#define T_MASK  0x1FFFF

// ---------------------------------------------------------------------------
// Small GEMM, LDS-staged output + fused row-dot-a:
//   Ya[m][:] = X[m][:] @ Wa         (stride lda) ; shOut[m] = Ya[m][:50].a
//   Yb[m][:] = X[m][:] @ Wb         (stride ldb) ; stOut[m] = Yb[m][:50].a
//   Yc[m][:] = X[m][:] @ Wc + bd    (stride ldc)   [NMAT==3 only]
// ---------------------------------------------------------------------------
template<int NMAT>
__global__ __launch_bounds__(256) void ent_pre_v4(
    const float* __restrict__ X, int ldX,
    const float* __restrict__ Wa,
    const float* __restrict__ Wb,
    const float* __restrict__ Wc,
    const float* __restrict__ bd,
    const float* __restrict__ avec,
    float* __restrict__ Ya, int lda,
    float* __restrict__ Yb, int ldb,
    float* __restrict__ Yc, int ldc,
    float* __restrict__ shOut,
    float* __restrict__ stOut)
{
    constexpr int MT = 20;       // rows per block; N_ENT % MT == 0
    __shared__ __align__(16) float sW[NMAT][DD * DD];
    __shared__ __align__(16) float sX[MT * 52];
    __shared__ __align__(16) float sY[MT * 64];
    __shared__ float sa[DD];

    const int tid = threadIdx.x;

    for (int i = tid; i < DD * DD / 4; i += 256) {
        ((float4*)sW[0])[i] = ((const float4*)Wa)[i];
        ((float4*)sW[1])[i] = ((const float4*)Wb)[i];
        if (NMAT == 3) ((float4*)sW[2])[i] = ((const float4*)Wc)[i];
    }
    if (tid < DD) sa[tid] = avec[tid];

    const int m0 = blockIdx.x * MT;
    const int nX4 = MT * ldX / 4;
    const float4* xsrc = (const float4*)(X + (size_t)m0 * ldX);
    for (int i = tid; i < nX4; i += 256) ((float4*)sX)[i] = xsrc[i];
    __syncthreads();

    const bool active = (tid < 250);
    const int mp = active ? tid / 25 : 0;
    const int jp = active ? tid % 25 : 0;
    const int r0 = 2 * mp, r1 = 2 * mp + 1, j0 = 2 * jp;

    float acc[NMAT][2][2];
    #pragma unroll
    for (int t = 0; t < NMAT; t++)
        #pragma unroll
        for (int i = 0; i < 2; i++)
            #pragma unroll
            for (int c = 0; c < 2; c++) acc[t][i][c] = 0.f;

    if (active) {
        if (NMAT == 3) {
            float b0 = bd[j0], b1 = bd[j0 + 1];
            acc[2][0][0] = b0; acc[2][0][1] = b1;
            acc[2][1][0] = b0; acc[2][1][1] = b1;
        }
        const float* xr0 = &sX[r0 * ldX];
        const float* xr1 = &sX[r1 * ldX];
        for (int k = 0; k < DD; k++) {
            float x0 = xr0[k], x1 = xr1[k];
            #pragma unroll
            for (int t = 0; t < NMAT; t++) {
                float2 w = *(const float2*)&sW[t][k * DD + j0];
                acc[t][0][0] += x0 * w.x; acc[t][0][1] += x0 * w.y;
                acc[t][1][0] += x1 * w.x; acc[t][1][1] += x1 * w.y;
            }
        }
    }

    #pragma unroll
    for (int t = 0; t < NMAT; t++) {
        if (t > 0) __syncthreads();
        const int ldt = (t == 0) ? lda : ((t == 1) ? ldb : ldc);
        const int pw = ldt - DD;
        for (int i = tid; i < MT * pw; i += 256)
            sY[(i / pw) * ldt + DD + (i % pw)] = 0.f;
        if (active) {
            sY[r0 * ldt + j0]     = acc[t][0][0];
            sY[r0 * ldt + j0 + 1] = acc[t][0][1];
            sY[r1 * ldt + j0]     = acc[t][1][0];
            sY[r1 * ldt + j0 + 1] = acc[t][1][1];
        }
        __syncthreads();
        float* Y = (t == 0) ? Ya : ((t == 1) ? Yb : Yc);
        float4* dst = (float4*)(Y + (size_t)m0 * ldt);
        for (int i = tid; i < MT * ldt / 4; i += 256) dst[i] = ((const float4*)sY)[i];
        float* dOut = (t == 0) ? shOut : ((t == 1) ? stOut : nullptr);
        if (dOut && tid < MT) {
            const float* row = &sY[tid * ldt];
            float d = 0.f;
            for (int k = 0; k < DD; k++) d += row[k] * sa[k];
            dOut[m0 + tid] = d;
        }
    }
}

// rel_out = (relu?) Rin @ Wr (stride ld_rel); RW_out = Rin @ Wmid (stride LD2)
__global__ void rel_pre_kernel(const float* __restrict__ Rin, int ld_in,
                               const float* __restrict__ Wr,
                               const float* __restrict__ Wmid,
                               int do_relu,
                               float* __restrict__ rel_out, int ld_rel,
                               float* __restrict__ RW_out)
{
    __shared__ float sWr[DD * DD];
    __shared__ float sWm[DD * DD];
    for (int i = threadIdx.x; i < DD * DD; i += blockDim.x) {
        sWr[i] = Wr[i];
        sWm[i] = Wmid[i];
    }
    __syncthreads();
    int idx = blockIdx.x * blockDim.x + threadIdx.x;
    if (idx >= N_REL * DD) return;
    int m = idx / DD, j = idx - m * DD;
    const float* x = Rin + (size_t)m * ld_in;
    float ar = 0.f, am = 0.f;
    for (int k = 0; k < DD; k++) {
        float xv = x[k];
        ar += xv * sWr[k * DD + j];
        am += xv * sWm[k * DD + j];
    }
    if (do_relu) ar = fmaxf(ar, 0.f);
    rel_out[(size_t)m * ld_rel + j] = ar;
    RW_out[(size_t)m * LD2 + j] = am;
    if (j < LD2 - DD) RW_out[(size_t)m * LD2 + DD + j] = 0.f;
}

// sr[m] = RW[m][:50] . a
__global__ void sr_kernel(const float* __restrict__ RW,
                          const float* __restrict__ avec,
                          float* __restrict__ sr)
{
    int m = blockIdx.x * blockDim.x + threadIdx.x;
    if (m >= N_REL) return;
    float d = 0.f;
    for (int k = 0; k < DD; k++) d += RW[(size_t)m * LD2 + k] * avec[k];
    sr[m] = d;
}

// ---------------------------------------------------------------------------
// CSR build: histogram -> per-wave base assignment (order-free) -> scatter
// ---------------------------------------------------------------------------
__global__ void hist_kernel(const int* __restrict__ h, int* __restrict__ counts, int nE)
{
    int e = blockIdx.x * blockDim.x + threadIdx.x;
    if (e < nE) atomicAdd(&counts[h[e]], 1);
}

__global__ void assign_kernel(const int* __restrict__ counts,
                              int* __restrict__ s0,
                              int* __restrict__ cursor,
                              int* __restrict__ total)
{
    int u = blockIdx.x * blockDim.x + threadIdx.x;
    int c = (u < N_ENT) ? counts[u] : 0;
    int lane = threadIdx.x & 63;
    int incl = c;
    #pragma unroll
    for (int off = 1; off < 64; off <<= 1) {
        int v = __shfl_up(incl, off);
        if (lane >= off) incl += v;
    }
    int wave_total = __shfl(incl, 63);
    int base = 0;
    if (lane == 63) base = atomicAdd(total, wave_total);
    base = __shfl(base, 63);
    if (u < N_ENT) {
        int b = base + incl - c;
        s0[u] = b;
        cursor[u] = b;
    }
}

// One packed 4 B store per edge: word = (r<<17)|t  (r<512, t<131072)
__global__ void scatter_kernel(const int* __restrict__ h,
                               const int* __restrict__ r,
                               const int* __restrict__ t,
                               int* __restrict__ cursor,
                               unsigned int* __restrict__ rtp, int nE)
{
    int e = blockIdx.x * blockDim.x + threadIdx.x;
    if (e >= nE) return;
    int u = h[e];
    unsigned int w = ((unsigned int)r[e] << T_BITS) | (unsigned int)t[e];
    int pos = atomicAdd(&cursor[u], 1);
    rtp[pos] = w;
}

// ---------------------------------------------------------------------------
// Unnormalized attention weights, head-parallel (1 pass):
//   ex = exp(leaky(sh[u] + sr[r] + st[t]))    (scores tiny -> no max needed)
// ---------------------------------------------------------------------------
__global__ void score_exp_kernel(const int* __restrict__ s0,
                                 const int* __restrict__ counts,
                                 const unsigned int* __restrict__ rtp,
                                 const float* __restrict__ sh,
                                 const float* __restrict__ sr,
                                 const float* __restrict__ st,
                                 float* __restrict__ ex)
{
    int u = blockIdx.x * blockDim.x + threadIdx.x;
    if (u >= N_ENT) return;
    int b = s0[u], c = counts[u];
    float shu = sh[u];
    for (int i = 0; i < c; i++) {
        unsigned int w = rtp[b + i];
        float sc = shu + sr[w >> T_BITS] + st[w & T_MASK];
        sc = sc >= 0.f ? sc : 0.2f * sc;
        ex[b + i] = __expf(sc);
    }
}

// ---------------------------------------------------------------------------
// Accumulate: thread per (u, j-quad):
//   out[u] = EW1[u] + (sum ex*(RW[r]+EW3[t])) / (sum ex)   (+ base[u])
// ---------------------------------------------------------------------------
__global__ void accum_kernel(const int* __restrict__ s0v,
                             const int* __restrict__ counts,
                             const unsigned int* __restrict__ rtp,
                             const float* __restrict__ ex,
                             const float* __restrict__ EW1,
                             const float* __restrict__ RW,
                             const float* __restrict__ EW3,
                             const float* __restrict__ base,
                             float* __restrict__ outp, int full_ld)
{
    int idx = blockIdx.x * blockDim.x + threadIdx.x;
    if (idx >= N_ENT * 13) return;
    int u = idx / 13, q = idx - u * 13;
    int s0 = s0v[u], s1 = s0 + counts[u];
    float4 acc = make_float4(0.f, 0.f, 0.f, 0.f);
    float asum = 0.f;
    for (int s = s0; s < s1; s++) {
        float al = ex[s];
        unsigned int w = rtp[s];
        float4 vr = *(const float4*)(RW  + (size_t)(w >> T_BITS) * LD2 + 4 * q);
        float4 vt = *(const float4*)(EW3 + (size_t)(w & T_MASK) * LD2 + 4 * q);
        asum += al;
        acc.x += al * (vr.x + vt.x);
        acc.y += al * (vr.y + vt.y);
        acc.z += al * (vr.z + vt.z);
        acc.w += al * (vr.w + vt.w);
    }
    if (asum > 0.f) {
        float inv = 1.f / asum;
        float4 w1 = *(const float4*)(EW1 + (size_t)u * LD + 4 * q);
        acc.x = w1.x + acc.x * inv;
        acc.y = w1.y + acc.y * inv;
        acc.z = w1.z + acc.z * inv;
        acc.w = w1.w + acc.w * inv;
    }  // else: empty segment -> 0, matching ref
    if (base) {
        float4 b = *(const float4*)(base + (size_t)u * LD + 4 * q);
        acc.x += b.x; acc.y += b.y; acc.z += b.z; acc.w += b.w;
    }
    if (full_ld) {
        *(float4*)(outp + (size_t)u * LD + 4 * q) = acc;
    } else {
        int j0 = 4 * q;
        float v[4] = { acc.x, acc.y, acc.z, acc.w };
        #pragma unroll
        for (int c = 0; c < 4; c++)
            if (j0 + c < DD) outp[(size_t)u * DD + j0 + c] = v[c];
    }
}

// ---------------------------------------------------------------------------
extern "C" void kernel_launch(void* const* d_in, const int* in_sizes, int n_in,
                              void* d_out, int out_size, void* d_ws, size_t ws_size,
                              hipStream_t stream)
{
    const int*   h   = (const int*)d_in[0];
    const int*   r   = (const int*)d_in[1];
    const int*   t   = (const int*)d_in[2];
    const float* E   = (const float*)d_in[3];
    const float* R   = (const float*)d_in[4];
    const float* W0  = (const float*)d_in[5];
    const float* a0  = (const float*)d_in[6];
    const float* Wr0 = (const float*)d_in[7];
    const float* W1  = (const float*)d_in[8];
    const float* a1  = (const float*)d_in[9];
    const float* Wr1 = (const float*)d_in[10];
    const float* Wd  = (const float*)d_in[11];
    const float* bd  = (const float*)d_in[12];

    float* out_ent = (float*)d_out;                 // [N_ENT, DD] stride DD
    float* out_rel = out_ent + (size_t)N_ENT * DD;  // [N_REL, DD] stride DD

    // workspace layout (~106 MB)
    float* ws_f  = (float*)d_ws;
    float* EW1   = ws_f;                         // N_ENT*LD
    float* Ed    = EW1  + (size_t)N_ENT * LD;    // N_ENT*LD
    float* e0    = Ed   + (size_t)N_ENT * LD;    // N_ENT*LD
    float* EW3   = e0   + (size_t)N_ENT * LD;    // N_ENT*LD2
    float* RW    = EW3  + (size_t)N_ENT * LD2;   // N_REL*LD2
    float* rel0  = RW   + (size_t)N_REL * LD2;   // N_REL*LD
    float* sh    = rel0 + (size_t)N_REL * LD;    // N_ENT
    float* st    = sh   + N_ENT;                 // N_ENT
    float* sr    = st   + N_ENT;                 // N_REL
    float* exv   = sr   + N_REL;                 // N_EDGES
    int* counts  = (int*)(exv + N_EDGES);        // N_ENT
    int* total   = counts + N_ENT;               // 1 (memset with counts)
    int* s0      = total + 1;                    // N_ENT
    int* cursor  = s0 + N_ENT;                   // N_ENT
    unsigned int* rtp = (unsigned int*)(cursor + N_ENT);  // N_EDGES packed (r,t)

    const int BLK = 256;
    const int gE   = (N_EDGES + BLK - 1) / BLK;
    const int gU   = (N_ENT + BLK - 1) / BLK;
    const int gUQ  = (N_ENT * 13 + BLK - 1) / BLK;
    const int gRD  = (N_REL * DD + BLK - 1) / BLK;
    const int gPRE = N_ENT / 20;

    // ---- CSR build (shared by both layers) ----
    hipMemsetAsync(counts, 0, (size_t)(N_ENT + 1) * sizeof(int), stream);
    hist_kernel<<<gE, BLK, 0, stream>>>(h, counts, N_EDGES);
    assign_kernel<<<gU, BLK, 0, stream>>>(counts, s0, cursor, total);
    scatter_kernel<<<gE, BLK, 0, stream>>>(h, r, t, cursor, rtp, N_EDGES);

    // ---- layer 0 precompute ----
    rel_pre_kernel<<<gRD, BLK, 0, stream>>>(R, DD, Wr0, W0 + DD * DD, 1,
                                            rel0, LD, RW);
    sr_kernel<<<2, BLK, 0, stream>>>(RW, a0, sr);
    ent_pre_v4<3><<<gPRE, BLK, 0, stream>>>(E, DD, W0, W0 + 2 * DD * DD, Wd, bd, a0,
                                            EW1, LD, EW3, LD2, Ed, LD, sh, st);

    // ---- layer 0 attention ----
    score_exp_kernel<<<gU, BLK, 0, stream>>>(s0, counts, rtp, sh, sr, st, exv);
    accum_kernel<<<gUQ, BLK, 0, stream>>>(s0, counts, rtp, exv,
                                          EW1, RW, EW3, nullptr, e0, 1);

    // ---- layer 1 precompute ----
    rel_pre_kernel<<<gRD, BLK, 0, stream>>>(rel0, LD, Wr1, W1 + DD * DD, 0,
                                            out_rel, DD, RW);
    sr_kernel<<<2, BLK, 0, stream>>>(RW, a1, sr);
    ent_pre_v4<2><<<gPRE, BLK, 0, stream>>>(e0, LD, W1, W1 + 2 * DD * DD,
                                            nullptr, nullptr, a1,
                                            EW1, LD, EW3, LD2, nullptr, LD, sh, st);

    // ---- layer 1 attention + fused residual ----
    score_exp_kernel<<<gU, BLK, 0, stream>>>(s0, counts, rtp, sh, sr, st, exv);
    accum_kernel<<<gUQ, BLK, 0, stream>>>(s0, counts, rtp, exv,
                                          EW1, RW, EW3, Ed, out_ent, 0);
}

// Round 7
// 647.647 us; speedup vs baseline: 4.6120x; 1.0825x over previous
//
#include <hip/hip_runtime.h>

#define N_ENT   100000
#define N_REL   500
#define DD      50
#define LD      52      // stride for sequentially-read tables (EW1/Ed/e0): 208 B
#define LD2     64      // stride for randomly-gathered tables (EW3/RW): 256 B = 2 lines
#define N_EDGES 2000000
#define T_BITS  17
#define T_MASK  0x1FFFF

// ---------------------------------------------------------------------------
// Small GEMM, LDS-staged output + fused row-dot-a:
//   Ya[m][:] = X[m][:] @ Wa         (stride lda) ; shOut[m] = Ya[m][:50].a
//   Yb[m][:] = X[m][:] @ Wb         (stride ldb) ; stOut[m] = Yb[m][:50].a
//   Yc[m][:] = X[m][:] @ Wc + bd    (stride ldc)   [NMAT==3 only]
// ---------------------------------------------------------------------------
template<int NMAT>
__global__ __launch_bounds__(256) void ent_pre_v4(
    const float* __restrict__ X, int ldX,
    const float* __restrict__ Wa,
    const float* __restrict__ Wb,
    const float* __restrict__ Wc,
    const float* __restrict__ bd,
    const float* __restrict__ avec,
    float* __restrict__ Ya, int lda,
    float* __restrict__ Yb, int ldb,
    float* __restrict__ Yc, int ldc,
    float* __restrict__ shOut,
    float* __restrict__ stOut)
{
    constexpr int MT = 20;       // rows per block; N_ENT % MT == 0
    __shared__ __align__(16) float sW[NMAT][DD * DD];
    __shared__ __align__(16) float sX[MT * 52];
    __shared__ __align__(16) float sY[MT * 64];
    __shared__ float sa[DD];

    const int tid = threadIdx.x;

    for (int i = tid; i < DD * DD / 4; i += 256) {
        ((float4*)sW[0])[i] = ((const float4*)Wa)[i];
        ((float4*)sW[1])[i] = ((const float4*)Wb)[i];
        if (NMAT == 3) ((float4*)sW[2])[i] = ((const float4*)Wc)[i];
    }
    if (tid < DD) sa[tid] = avec[tid];

    const int m0 = blockIdx.x * MT;
    const int nX4 = MT * ldX / 4;
    const float4* xsrc = (const float4*)(X + (size_t)m0 * ldX);
    for (int i = tid; i < nX4; i += 256) ((float4*)sX)[i] = xsrc[i];
    __syncthreads();

    const bool active = (tid < 250);
    const int mp = active ? tid / 25 : 0;
    const int jp = active ? tid % 25 : 0;
    const int r0 = 2 * mp, r1 = 2 * mp + 1, j0 = 2 * jp;

    float acc[NMAT][2][2];
    #pragma unroll
    for (int t = 0; t < NMAT; t++)
        #pragma unroll
        for (int i = 0; i < 2; i++)
            #pragma unroll
            for (int c = 0; c < 2; c++) acc[t][i][c] = 0.f;

    if (active) {
        if (NMAT == 3) {
            float b0 = bd[j0], b1 = bd[j0 + 1];
            acc[2][0][0] = b0; acc[2][0][1] = b1;
            acc[2][1][0] = b0; acc[2][1][1] = b1;
        }
        const float* xr0 = &sX[r0 * ldX];
        const float* xr1 = &sX[r1 * ldX];
        for (int k = 0; k < DD; k++) {
            float x0 = xr0[k], x1 = xr1[k];
            #pragma unroll
            for (int t = 0; t < NMAT; t++) {
                float2 w = *(const float2*)&sW[t][k * DD + j0];
                acc[t][0][0] += x0 * w.x; acc[t][0][1] += x0 * w.y;
                acc[t][1][0] += x1 * w.x; acc[t][1][1] += x1 * w.y;
            }
        }
    }

    #pragma unroll
    for (int t = 0; t < NMAT; t++) {
        if (t > 0) __syncthreads();
        const int ldt = (t == 0) ? lda : ((t == 1) ? ldb : ldc);
        const int pw = ldt - DD;
        for (int i = tid; i < MT * pw; i += 256)
            sY[(i / pw) * ldt + DD + (i % pw)] = 0.f;
        if (active) {
            sY[r0 * ldt + j0]     = acc[t][0][0];
            sY[r0 * ldt + j0 + 1] = acc[t][0][1];
            sY[r1 * ldt + j0]     = acc[t][1][0];
            sY[r1 * ldt + j0 + 1] = acc[t][1][1];
        }
        __syncthreads();
        float* Y = (t == 0) ? Ya : ((t == 1) ? Yb : Yc);
        float4* dst = (float4*)(Y + (size_t)m0 * ldt);
        for (int i = tid; i < MT * ldt / 4; i += 256) dst[i] = ((const float4*)sY)[i];
        float* dOut = (t == 0) ? shOut : ((t == 1) ? stOut : nullptr);
        if (dOut && tid < MT) {
            const float* row = &sY[tid * ldt];
            float d = 0.f;
            for (int k = 0; k < DD; k++) d += row[k] * sa[k];
            dOut[m0 + tid] = d;
        }
    }
}

// rel_out = (relu?) Rin @ Wr (stride ld_rel); RW_out = Rin @ Wmid (stride LD2)
__global__ void rel_pre_kernel(const float* __restrict__ Rin, int ld_in,
                               const float* __restrict__ Wr,
                               const float* __restrict__ Wmid,
                               int do_relu,
                               float* __restrict__ rel_out, int ld_rel,
                               float* __restrict__ RW_out)
{
    __shared__ float sWr[DD * DD];
    __shared__ float sWm[DD * DD];
    for (int i = threadIdx.x; i < DD * DD; i += blockDim.x) {
        sWr[i] = Wr[i];
        sWm[i] = Wmid[i];
    }
    __syncthreads();
    int idx = blockIdx.x * blockDim.x + threadIdx.x;
    if (idx >= N_REL * DD) return;
    int m = idx / DD, j = idx - m * DD;
    const float* x = Rin + (size_t)m * ld_in;
    float ar = 0.f, am = 0.f;
    for (int k = 0; k < DD; k++) {
        float xv = x[k];
        ar += xv * sWr[k * DD + j];
        am += xv * sWm[k * DD + j];
    }
    if (do_relu) ar = fmaxf(ar, 0.f);
    rel_out[(size_t)m * ld_rel + j] = ar;
    RW_out[(size_t)m * LD2 + j] = am;
    if (j < LD2 - DD) RW_out[(size_t)m * LD2 + DD + j] = 0.f;
}

// sr[m] = RW[m][:50] . a
__global__ void sr_kernel(const float* __restrict__ RW,
                          const float* __restrict__ avec,
                          float* __restrict__ sr)
{
    int m = blockIdx.x * blockDim.x + threadIdx.x;
    if (m >= N_REL) return;
    float d = 0.f;
    for (int k = 0; k < DD; k++) d += RW[(size_t)m * LD2 + k] * avec[k];
    sr[m] = d;
}

// ---------------------------------------------------------------------------
// CSR build: histogram -> per-wave base assignment (order-free) -> scatter
// ---------------------------------------------------------------------------
__global__ void hist_kernel(const int* __restrict__ h, int* __restrict__ counts, int nE)
{
    int e = blockIdx.x * blockDim.x + threadIdx.x;
    if (e < nE) atomicAdd(&counts[h[e]], 1);
}

__global__ void assign_kernel(const int* __restrict__ counts,
                              int* __restrict__ s0,
                              int* __restrict__ cursor,
                              int* __restrict__ total)
{
    int u = blockIdx.x * blockDim.x + threadIdx.x;
    int c = (u < N_ENT) ? counts[u] : 0;
    int lane = threadIdx.x & 63;
    int incl = c;
    #pragma unroll
    for (int off = 1; off < 64; off <<= 1) {
        int v = __shfl_up(incl, off);
        if (lane >= off) incl += v;
    }
    int wave_total = __shfl(incl, 63);
    int base = 0;
    if (lane == 63) base = atomicAdd(total, wave_total);
    base = __shfl(base, 63);
    if (u < N_ENT) {
        int b = base + incl - c;
        s0[u] = b;
        cursor[u] = b;
    }
}

// One packed 4 B store per edge: word = (r<<17)|t  (r<512, t<131072)
__global__ void scatter_kernel(const int* __restrict__ h,
                               const int* __restrict__ r,
                               const int* __restrict__ t,
                               int* __restrict__ cursor,
                               unsigned int* __restrict__ rtp, int nE)
{
    int e = blockIdx.x * blockDim.x + threadIdx.x;
    if (e >= nE) return;
    int u = h[e];
    unsigned int w = ((unsigned int)r[e] << T_BITS) | (unsigned int)t[e];
    int pos = atomicAdd(&cursor[u], 1);
    rtp[pos] = w;
}

// ---------------------------------------------------------------------------
// Fused score + accumulate, one WAVE per head.
// Lanes: eg = lane/13 in 0..3 (edge group), q = lane%13 (j-quad); 52 active.
// Per edge: ex = exp(leaky(sh[u]+sr[r]+st[t])) computed in-lane; row gathers
// of RW/EW3 coalesced 208 B across the 13 q-lanes.
// Cross-lane shfl_down(26,13) folds the 4 edge groups for acc AND asum
// (all 13 lanes of an eg carry the same ex, so per-q asum reduces exactly).
//   out[u] = EW1[u] + (sum ex*(RW[r]+EW3[t])) / (sum ex)   (+ base[u])
// ---------------------------------------------------------------------------
__global__ __launch_bounds__(256) void accum_fused_kernel(
    const int* __restrict__ s0v,
    const int* __restrict__ counts,
    const unsigned int* __restrict__ rtp,
    const float* __restrict__ sh,
    const float* __restrict__ sr,
    const float* __restrict__ st,
    const float* __restrict__ EW1,
    const float* __restrict__ RW,
    const float* __restrict__ EW3,
    const float* __restrict__ base,
    float* __restrict__ outp, int full_ld)
{
    const int u = (blockIdx.x * blockDim.x + threadIdx.x) >> 6;  // wave id
    if (u >= N_ENT) return;            // grid exact: uniform per wave
    const int lane = threadIdx.x & 63;
    const int eg = lane / 13;          // 0..4 (eg==4 -> lanes 52..63 idle)
    const int q  = lane - eg * 13;

    const int b = s0v[u];
    const int c = counts[u];
    const float shu = sh[u];

    float4 acc = make_float4(0.f, 0.f, 0.f, 0.f);
    float asum = 0.f;

    if (eg < 4) {
        for (int i = eg; i < c; i += 4) {
            unsigned int w = rtp[b + i];
            int rr = w >> T_BITS;
            int tt = w & T_MASK;
            float sc = shu + sr[rr] + st[tt];
            sc = sc >= 0.f ? sc : 0.2f * sc;
            float ex = __expf(sc);
            float4 vr = *(const float4*)(RW  + (size_t)rr * LD2 + 4 * q);
            float4 vt = *(const float4*)(EW3 + (size_t)tt * LD2 + 4 * q);
            asum += ex;
            acc.x += ex * (vr.x + vt.x);
            acc.y += ex * (vr.y + vt.y);
            acc.z += ex * (vr.z + vt.z);
            acc.w += ex * (vr.w + vt.w);
        }
    }

    // fold eg2/eg3 into eg0/eg1, then eg1 into eg0
    acc.x += __shfl_down(acc.x, 26); acc.y += __shfl_down(acc.y, 26);
    acc.z += __shfl_down(acc.z, 26); acc.w += __shfl_down(acc.w, 26);
    asum  += __shfl_down(asum, 26);
    acc.x += __shfl_down(acc.x, 13); acc.y += __shfl_down(acc.y, 13);
    acc.z += __shfl_down(acc.z, 13); acc.w += __shfl_down(acc.w, 13);
    asum  += __shfl_down(asum, 13);

    if (lane >= 13) return;            // lanes 0..12 hold quad `lane`

    if (asum > 0.f) {
        float inv = 1.f / asum;
        float4 w1 = *(const float4*)(EW1 + (size_t)u * LD + 4 * lane);
        acc.x = w1.x + acc.x * inv;
        acc.y = w1.y + acc.y * inv;
        acc.z = w1.z + acc.z * inv;
        acc.w = w1.w + acc.w * inv;
    }  // else: empty segment -> 0, matching ref
    if (base) {
        float4 bb = *(const float4*)(base + (size_t)u * LD + 4 * lane);
        acc.x += bb.x; acc.y += bb.y; acc.z += bb.z; acc.w += bb.w;
    }
    if (full_ld) {
        *(float4*)(outp + (size_t)u * LD + 4 * lane) = acc;  // 13x16B = full row
    } else {
        int j0 = 4 * lane;
        float v[4] = { acc.x, acc.y, acc.z, acc.w };
        #pragma unroll
        for (int cc = 0; cc < 4; cc++)
            if (j0 + cc < DD) outp[(size_t)u * DD + j0 + cc] = v[cc];
    }
}

// ---------------------------------------------------------------------------
extern "C" void kernel_launch(void* const* d_in, const int* in_sizes, int n_in,
                              void* d_out, int out_size, void* d_ws, size_t ws_size,
                              hipStream_t stream)
{
    const int*   h   = (const int*)d_in[0];
    const int*   r   = (const int*)d_in[1];
    const int*   t   = (const int*)d_in[2];
    const float* E   = (const float*)d_in[3];
    const float* R   = (const float*)d_in[4];
    const float* W0  = (const float*)d_in[5];
    const float* a0  = (const float*)d_in[6];
    const float* Wr0 = (const float*)d_in[7];
    const float* W1  = (const float*)d_in[8];
    const float* a1  = (const float*)d_in[9];
    const float* Wr1 = (const float*)d_in[10];
    const float* Wd  = (const float*)d_in[11];
    const float* bd  = (const float*)d_in[12];

    float* out_ent = (float*)d_out;                 // [N_ENT, DD] stride DD
    float* out_rel = out_ent + (size_t)N_ENT * DD;  // [N_REL, DD] stride DD

    // workspace layout (~98 MB)
    float* ws_f  = (float*)d_ws;
    float* EW1   = ws_f;                         // N_ENT*LD
    float* Ed    = EW1  + (size_t)N_ENT * LD;    // N_ENT*LD
    float* e0    = Ed   + (size_t)N_ENT * LD;    // N_ENT*LD
    float* EW3   = e0   + (size_t)N_ENT * LD;    // N_ENT*LD2
    float* RW    = EW3  + (size_t)N_ENT * LD2;   // N_REL*LD2
    float* rel0  = RW   + (size_t)N_REL * LD2;   // N_REL*LD
    float* sh    = rel0 + (size_t)N_REL * LD;    // N_ENT
    float* st    = sh   + N_ENT;                 // N_ENT
    float* sr    = st   + N_ENT;                 // N_REL
    int* counts  = (int*)(sr + N_REL);           // N_ENT
    int* total   = counts + N_ENT;               // 1 (memset with counts)
    int* s0      = total + 1;                    // N_ENT
    int* cursor  = s0 + N_ENT;                   // N_ENT
    unsigned int* rtp = (unsigned int*)(cursor + N_ENT);  // N_EDGES packed (r,t)

    const int BLK = 256;
    const int gE   = (N_EDGES + BLK - 1) / BLK;
    const int gU   = (N_ENT + BLK - 1) / BLK;
    const int gW   = (N_ENT + 3) / 4;            // 1 wave per head, 4 waves/block
    const int gRD  = (N_REL * DD + BLK - 1) / BLK;
    const int gPRE = N_ENT / 20;

    // ---- CSR build (shared by both layers) ----
    hipMemsetAsync(counts, 0, (size_t)(N_ENT + 1) * sizeof(int), stream);
    hist_kernel<<<gE, BLK, 0, stream>>>(h, counts, N_EDGES);
    assign_kernel<<<gU, BLK, 0, stream>>>(counts, s0, cursor, total);
    scatter_kernel<<<gE, BLK, 0, stream>>>(h, r, t, cursor, rtp, N_EDGES);

    // ---- layer 0 precompute ----
    rel_pre_kernel<<<gRD, BLK, 0, stream>>>(R, DD, Wr0, W0 + DD * DD, 1,
                                            rel0, LD, RW);
    sr_kernel<<<2, BLK, 0, stream>>>(RW, a0, sr);
    ent_pre_v4<3><<<gPRE, BLK, 0, stream>>>(E, DD, W0, W0 + 2 * DD * DD, Wd, bd, a0,
                                            EW1, LD, EW3, LD2, Ed, LD, sh, st);

    // ---- layer 0 attention (fused score+softmax+accumulate) ----
    accum_fused_kernel<<<gW, BLK, 0, stream>>>(s0, counts, rtp, sh, sr, st,
                                               EW1, RW, EW3, nullptr, e0, 1);

    // ---- layer 1 precompute ----
    rel_pre_kernel<<<gRD, BLK, 0, stream>>>(rel0, LD, Wr1, W1 + DD * DD, 0,
                                            out_rel, DD, RW);
    sr_kernel<<<2, BLK, 0, stream>>>(RW, a1, sr);
    ent_pre_v4<2><<<gPRE, BLK, 0, stream>>>(e0, LD, W1, W1 + 2 * DD * DD,
                                            nullptr, nullptr, a1,
                                            EW1, LD, EW3, LD2, nullptr, LD, sh, st);

    // ---- layer 1 attention + fused residual ----
    accum_fused_kernel<<<gW, BLK, 0, stream>>>(s0, counts, rtp, sh, sr, st,
                                               EW1, RW, EW3, Ed, out_ent, 0);
}

// Round 8
// 637.363 us; speedup vs baseline: 4.6864x; 1.0161x over previous
//
#include <hip/hip_runtime.h>

#define N_ENT   100000
#define N_REL   500
#define DD      50
#define LD      52      // stride for sequentially-read tables (EW1/Ed/e0): 208 B
#define LD2     64      // stride for randomly-gathered tables (EW3/RW): 256 B = 2 lines
#define N_EDGES 2000000
#define T_BITS  17
#define T_MASK  0x1FFFF
#define BBITS   9                    // 512 entities per coarse bucket
#define BMASK   511
#define NB      196                  // ceil(N_ENT / 512)
#define CHUNK   8192                 // edges per bucket_scatter block

// ---------------------------------------------------------------------------
// Small GEMM, LDS-staged output + fused row-dot-a:
//   Ya[m][:] = X[m][:] @ Wa         (stride lda) ; shOut[m] = Ya[m][:50].a
//   Yb[m][:] = X[m][:] @ Wb         (stride ldb) ; stOut[m] = Yb[m][:50].a
//   Yc[m][:] = X[m][:] @ Wc + bd    (stride ldc)   [NMAT==3 only]
// ---------------------------------------------------------------------------
template<int NMAT>
__global__ __launch_bounds__(256) void ent_pre_v4(
    const float* __restrict__ X, int ldX,
    const float* __restrict__ Wa,
    const float* __restrict__ Wb,
    const float* __restrict__ Wc,
    const float* __restrict__ bd,
    const float* __restrict__ avec,
    float* __restrict__ Ya, int lda,
    float* __restrict__ Yb, int ldb,
    float* __restrict__ Yc, int ldc,
    float* __restrict__ shOut,
    float* __restrict__ stOut)
{
    constexpr int MT = 20;       // rows per block; N_ENT % MT == 0
    __shared__ __align__(16) float sW[NMAT][DD * DD];
    __shared__ __align__(16) float sX[MT * 52];
    __shared__ __align__(16) float sY[MT * 64];
    __shared__ float sa[DD];

    const int tid = threadIdx.x;

    for (int i = tid; i < DD * DD / 4; i += 256) {
        ((float4*)sW[0])[i] = ((const float4*)Wa)[i];
        ((float4*)sW[1])[i] = ((const float4*)Wb)[i];
        if (NMAT == 3) ((float4*)sW[2])[i] = ((const float4*)Wc)[i];
    }
    if (tid < DD) sa[tid] = avec[tid];

    const int m0 = blockIdx.x * MT;
    const int nX4 = MT * ldX / 4;
    const float4* xsrc = (const float4*)(X + (size_t)m0 * ldX);
    for (int i = tid; i < nX4; i += 256) ((float4*)sX)[i] = xsrc[i];
    __syncthreads();

    const bool active = (tid < 250);
    const int mp = active ? tid / 25 : 0;
    const int jp = active ? tid % 25 : 0;
    const int r0 = 2 * mp, r1 = 2 * mp + 1, j0 = 2 * jp;

    float acc[NMAT][2][2];
    #pragma unroll
    for (int t = 0; t < NMAT; t++)
        #pragma unroll
        for (int i = 0; i < 2; i++)
            #pragma unroll
            for (int c = 0; c < 2; c++) acc[t][i][c] = 0.f;

    if (active) {
        if (NMAT == 3) {
            float b0 = bd[j0], b1 = bd[j0 + 1];
            acc[2][0][0] = b0; acc[2][0][1] = b1;
            acc[2][1][0] = b0; acc[2][1][1] = b1;
        }
        const float* xr0 = &sX[r0 * ldX];
        const float* xr1 = &sX[r1 * ldX];
        for (int k = 0; k < DD; k++) {
            float x0 = xr0[k], x1 = xr1[k];
            #pragma unroll
            for (int t = 0; t < NMAT; t++) {
                float2 w = *(const float2*)&sW[t][k * DD + j0];
                acc[t][0][0] += x0 * w.x; acc[t][0][1] += x0 * w.y;
                acc[t][1][0] += x1 * w.x; acc[t][1][1] += x1 * w.y;
            }
        }
    }

    #pragma unroll
    for (int t = 0; t < NMAT; t++) {
        if (t > 0) __syncthreads();
        const int ldt = (t == 0) ? lda : ((t == 1) ? ldb : ldc);
        const int pw = ldt - DD;
        for (int i = tid; i < MT * pw; i += 256)
            sY[(i / pw) * ldt + DD + (i % pw)] = 0.f;
        if (active) {
            sY[r0 * ldt + j0]     = acc[t][0][0];
            sY[r0 * ldt + j0 + 1] = acc[t][0][1];
            sY[r1 * ldt + j0]     = acc[t][1][0];
            sY[r1 * ldt + j0 + 1] = acc[t][1][1];
        }
        __syncthreads();
        float* Y = (t == 0) ? Ya : ((t == 1) ? Yb : Yc);
        float4* dst = (float4*)(Y + (size_t)m0 * ldt);
        for (int i = tid; i < MT * ldt / 4; i += 256) dst[i] = ((const float4*)sY)[i];
        float* dOut = (t == 0) ? shOut : ((t == 1) ? stOut : nullptr);
        if (dOut && tid < MT) {
            const float* row = &sY[tid * ldt];
            float d = 0.f;
            for (int k = 0; k < DD; k++) d += row[k] * sa[k];
            dOut[m0 + tid] = d;
        }
    }
}

// rel_out = (relu?) Rin @ Wr (stride ld_rel); RW_out = Rin @ Wmid (stride LD2)
__global__ void rel_pre_kernel(const float* __restrict__ Rin, int ld_in,
                               const float* __restrict__ Wr,
                               const float* __restrict__ Wmid,
                               int do_relu,
                               float* __restrict__ rel_out, int ld_rel,
                               float* __restrict__ RW_out)
{
    __shared__ float sWr[DD * DD];
    __shared__ float sWm[DD * DD];
    for (int i = threadIdx.x; i < DD * DD; i += blockDim.x) {
        sWr[i] = Wr[i];
        sWm[i] = Wmid[i];
    }
    __syncthreads();
    int idx = blockIdx.x * blockDim.x + threadIdx.x;
    if (idx >= N_REL * DD) return;
    int m = idx / DD, j = idx - m * DD;
    const float* x = Rin + (size_t)m * ld_in;
    float ar = 0.f, am = 0.f;
    for (int k = 0; k < DD; k++) {
        float xv = x[k];
        ar += xv * sWr[k * DD + j];
        am += xv * sWm[k * DD + j];
    }
    if (do_relu) ar = fmaxf(ar, 0.f);
    rel_out[(size_t)m * ld_rel + j] = ar;
    RW_out[(size_t)m * LD2 + j] = am;
    if (j < LD2 - DD) RW_out[(size_t)m * LD2 + DD + j] = 0.f;
}

// sr[m] = RW[m][:50] . a
__global__ void sr_kernel(const float* __restrict__ RW,
                          const float* __restrict__ avec,
                          float* __restrict__ sr)
{
    int m = blockIdx.x * blockDim.x + threadIdx.x;
    if (m >= N_REL) return;
    float d = 0.f;
    for (int k = 0; k < DD; k++) d += RW[(size_t)m * LD2 + k] * avec[k];
    sr[m] = d;
}

// ---------------------------------------------------------------------------
// CSR build, two-level multisplit (line-dense writes):
//   hist -> coarse scan -> per-bucket entity prefix -> bucket scatter -> exact
// ---------------------------------------------------------------------------
__global__ void hist_kernel(const int* __restrict__ h, int* __restrict__ counts, int nE)
{
    int e = blockIdx.x * blockDim.x + threadIdx.x;
    if (e < nE) atomicAdd(&counts[h[e]], 1);
}

// One block: coarse bucket sums + exclusive scan -> cbase[NB+1], ccur[NB]
__global__ void coarse_kernel(const int* __restrict__ counts,
                              int* __restrict__ cbase,
                              int* __restrict__ ccur)
{
    __shared__ int s[256];
    const int b = threadIdx.x;
    int sum = 0;
    if (b < NB) {
        const int u0 = b << BBITS;
        const int nm = min(512, N_ENT - u0);        // 512 or 160, both %4==0
        const int4* c4 = (const int4*)(counts + u0);
        for (int k = 0; k < nm / 4; k++) {
            int4 v = c4[k];
            sum += v.x + v.y + v.z + v.w;
        }
    }
    s[b] = sum;
    __syncthreads();
    for (int off = 1; off < 256; off <<= 1) {
        int v = (b >= off) ? s[b - off] : 0;
        __syncthreads();
        s[b] += v;
        __syncthreads();
    }
    if (b < NB) {
        int excl = s[b] - sum;
        cbase[b] = excl;
        ccur[b] = excl;
    }
    if (b == NB - 1) cbase[NB] = s[b];
}

// One wave per bucket: globally-ordered s0[u]/cursor[u] (bucket windows contiguous)
__global__ void assign2_kernel(const int* __restrict__ counts,
                               const int* __restrict__ cbase,
                               int* __restrict__ s0,
                               int* __restrict__ cursor)
{
    const int w = (blockIdx.x * blockDim.x + threadIdx.x) >> 6;
    if (w >= NB) return;
    const int lane = threadIdx.x & 63;
    const int u0 = (w << BBITS) + lane * 8;
    int pre[8];
    int s = 0;
    #pragma unroll
    for (int k = 0; k < 8; k++) {
        int u = u0 + k;
        int c = (u < N_ENT) ? counts[u] : 0;
        pre[k] = s;
        s += c;
    }
    int incl = s;
    #pragma unroll
    for (int off = 1; off < 64; off <<= 1) {
        int v = __shfl_up(incl, off);
        if (lane >= off) incl += v;
    }
    const int base = cbase[w] + incl - s;
    #pragma unroll
    for (int k = 0; k < 8; k++) {
        int u = u0 + k;
        if (u < N_ENT) {
            s0[u] = base + pre[k];
            cursor[u] = base + pre[k];
        }
    }
}

// S1: LDS multisplit of 8192-edge chunks into NB staged bucket regions.
// staged word = (e << 9) | (h & 511)   (21 + 9 = 30 bits)
__global__ __launch_bounds__(256) void bucket_scatter_kernel(
    const int* __restrict__ h,
    int* __restrict__ ccur,
    unsigned int* __restrict__ staged, int nE)
{
    __shared__ int sHist[NB];
    __shared__ int sScan[256];
    __shared__ int sBase[NB];
    __shared__ int sCur[NB];
    __shared__ int sGb[NB];
    __shared__ unsigned int sBuf[CHUNK];
    __shared__ unsigned char sBkt[CHUNK];

    const int tid = threadIdx.x;
    const int e0 = blockIdx.x * CHUNK;
    const int n = min(CHUNK, nE - e0);

    for (int i = tid; i < NB; i += 256) sHist[i] = 0;
    __syncthreads();

    #pragma unroll
    for (int k = 0; k < CHUNK / 256; k++) {
        int e = e0 + k * 256 + tid;
        if (e < nE) atomicAdd(&sHist[h[e] >> BBITS], 1);
    }
    __syncthreads();

    int v = (tid < NB) ? sHist[tid] : 0;
    sScan[tid] = v;
    __syncthreads();
    for (int off = 1; off < 256; off <<= 1) {
        int x = (tid >= off) ? sScan[tid - off] : 0;
        __syncthreads();
        sScan[tid] += x;
        __syncthreads();
    }
    if (tid < NB) {
        int excl = sScan[tid] - v;
        sBase[tid] = excl;
        sCur[tid] = excl;
    }
    __syncthreads();

    #pragma unroll
    for (int k = 0; k < CHUNK / 256; k++) {
        int e = e0 + k * 256 + tid;
        if (e < nE) {
            int hv = h[e];
            int b = hv >> BBITS;
            int pos = atomicAdd(&sCur[b], 1);
            sBuf[pos] = ((unsigned int)e << BBITS) | (unsigned int)(hv & BMASK);
            sBkt[pos] = (unsigned char)b;
        }
    }
    __syncthreads();

    if (tid < NB) {
        int cnt = sHist[tid];
        sGb[tid] = cnt ? atomicAdd(&ccur[tid], cnt) : 0;
    }
    __syncthreads();

    for (int i = tid; i < n; i += 256) {
        int b = sBkt[i];
        staged[sGb[b] + (i - sBase[b])] = sBuf[i];
    }
}

// S2: one block per bucket; exact placement into the bucket's contiguous
// rtp window (writes stay L2-resident until lines are fully populated).
__global__ void final_scatter_kernel(const unsigned int* __restrict__ staged,
                                     const int* __restrict__ cbase,
                                     const int* __restrict__ r,
                                     const int* __restrict__ t,
                                     int* __restrict__ cursor,
                                     unsigned int* __restrict__ rtp)
{
    const int b = blockIdx.x;
    const int i0 = cbase[b], i1 = cbase[b + 1];
    for (int i = i0 + threadIdx.x; i < i1; i += 256) {
        unsigned int w = staged[i];
        int e = w >> BBITS;
        int u = (b << BBITS) | (int)(w & BMASK);
        int pos = atomicAdd(&cursor[u], 1);
        rtp[pos] = ((unsigned int)r[e] << T_BITS) | (unsigned int)t[e];
    }
}

// ---------------------------------------------------------------------------
// Fused score + accumulate, one WAVE per head (unchanged from R7).
// ---------------------------------------------------------------------------
__global__ __launch_bounds__(256) void accum_fused_kernel(
    const int* __restrict__ s0v,
    const int* __restrict__ counts,
    const unsigned int* __restrict__ rtp,
    const float* __restrict__ sh,
    const float* __restrict__ sr,
    const float* __restrict__ st,
    const float* __restrict__ EW1,
    const float* __restrict__ RW,
    const float* __restrict__ EW3,
    const float* __restrict__ base,
    float* __restrict__ outp, int full_ld)
{
    const int u = (blockIdx.x * blockDim.x + threadIdx.x) >> 6;  // wave id
    if (u >= N_ENT) return;
    const int lane = threadIdx.x & 63;
    const int eg = lane / 13;          // 0..4 (eg==4 -> lanes 52..63 idle)
    const int q  = lane - eg * 13;

    const int b = s0v[u];
    const int c = counts[u];
    const float shu = sh[u];

    float4 acc = make_float4(0.f, 0.f, 0.f, 0.f);
    float asum = 0.f;

    if (eg < 4) {
        for (int i = eg; i < c; i += 4) {
            unsigned int w = rtp[b + i];
            int rr = w >> T_BITS;
            int tt = w & T_MASK;
            float sc = shu + sr[rr] + st[tt];
            sc = sc >= 0.f ? sc : 0.2f * sc;
            float ex = __expf(sc);
            float4 vr = *(const float4*)(RW  + (size_t)rr * LD2 + 4 * q);
            float4 vt = *(const float4*)(EW3 + (size_t)tt * LD2 + 4 * q);
            asum += ex;
            acc.x += ex * (vr.x + vt.x);
            acc.y += ex * (vr.y + vt.y);
            acc.z += ex * (vr.z + vt.z);
            acc.w += ex * (vr.w + vt.w);
        }
    }

    acc.x += __shfl_down(acc.x, 26); acc.y += __shfl_down(acc.y, 26);
    acc.z += __shfl_down(acc.z, 26); acc.w += __shfl_down(acc.w, 26);
    asum  += __shfl_down(asum, 26);
    acc.x += __shfl_down(acc.x, 13); acc.y += __shfl_down(acc.y, 13);
    acc.z += __shfl_down(acc.z, 13); acc.w += __shfl_down(acc.w, 13);
    asum  += __shfl_down(asum, 13);

    if (lane >= 13) return;

    if (asum > 0.f) {
        float inv = 1.f / asum;
        float4 w1 = *(const float4*)(EW1 + (size_t)u * LD + 4 * lane);
        acc.x = w1.x + acc.x * inv;
        acc.y = w1.y + acc.y * inv;
        acc.z = w1.z + acc.z * inv;
        acc.w = w1.w + acc.w * inv;
    }
    if (base) {
        float4 bb = *(const float4*)(base + (size_t)u * LD + 4 * lane);
        acc.x += bb.x; acc.y += bb.y; acc.z += bb.z; acc.w += bb.w;
    }
    if (full_ld) {
        *(float4*)(outp + (size_t)u * LD + 4 * lane) = acc;
    } else {
        int j0 = 4 * lane;
        float v[4] = { acc.x, acc.y, acc.z, acc.w };
        #pragma unroll
        for (int cc = 0; cc < 4; cc++)
            if (j0 + cc < DD) outp[(size_t)u * DD + j0 + cc] = v[cc];
    }
}

// ---------------------------------------------------------------------------
extern "C" void kernel_launch(void* const* d_in, const int* in_sizes, int n_in,
                              void* d_out, int out_size, void* d_ws, size_t ws_size,
                              hipStream_t stream)
{
    const int*   h   = (const int*)d_in[0];
    const int*   r   = (const int*)d_in[1];
    const int*   t   = (const int*)d_in[2];
    const float* E   = (const float*)d_in[3];
    const float* R   = (const float*)d_in[4];
    const float* W0  = (const float*)d_in[5];
    const float* a0  = (const float*)d_in[6];
    const float* Wr0 = (const float*)d_in[7];
    const float* W1  = (const float*)d_in[8];
    const float* a1  = (const float*)d_in[9];
    const float* Wr1 = (const float*)d_in[10];
    const float* Wd  = (const float*)d_in[11];
    const float* bd  = (const float*)d_in[12];

    float* out_ent = (float*)d_out;                 // [N_ENT, DD] stride DD
    float* out_rel = out_ent + (size_t)N_ENT * DD;  // [N_REL, DD] stride DD

    // workspace layout (~106 MB)
    float* ws_f  = (float*)d_ws;
    float* EW1   = ws_f;                         // N_ENT*LD
    float* Ed    = EW1  + (size_t)N_ENT * LD;    // N_ENT*LD
    float* e0    = Ed   + (size_t)N_ENT * LD;    // N_ENT*LD
    float* EW3   = e0   + (size_t)N_ENT * LD;    // N_ENT*LD2
    float* RW    = EW3  + (size_t)N_ENT * LD2;   // N_REL*LD2
    float* rel0  = RW   + (size_t)N_REL * LD2;   // N_REL*LD
    float* sh    = rel0 + (size_t)N_REL * LD;    // N_ENT
    float* st    = sh   + N_ENT;                 // N_ENT
    float* sr    = st   + N_ENT;                 // N_REL
    int* counts  = (int*)(sr + N_REL);           // N_ENT
    int* s0      = counts + N_ENT;               // N_ENT
    int* cursor  = s0 + N_ENT;                   // N_ENT
    int* cbase   = cursor + N_ENT;               // NB+1
    int* ccur    = cbase + NB + 1;               // NB
    unsigned int* rtp    = (unsigned int*)(ccur + NB);   // N_EDGES
    unsigned int* staged = rtp + N_EDGES;                // N_EDGES

    const int BLK = 256;
    const int gE   = (N_EDGES + BLK - 1) / BLK;
    const int gW   = (N_ENT + 3) / 4;            // accum: 1 wave/head, 4 waves/blk
    const int gRD  = (N_REL * DD + BLK - 1) / BLK;
    const int gPRE = N_ENT / 20;
    const int gS1  = (N_EDGES + CHUNK - 1) / CHUNK;   // 245
    const int gA2  = (NB + 3) / 4;                    // 49 blocks = 196 waves

    // ---- CSR build (two-level multisplit; shared by both layers) ----
    hipMemsetAsync(counts, 0, (size_t)N_ENT * sizeof(int), stream);
    hist_kernel<<<gE, BLK, 0, stream>>>(h, counts, N_EDGES);
    coarse_kernel<<<1, 256, 0, stream>>>(counts, cbase, ccur);
    assign2_kernel<<<gA2, BLK, 0, stream>>>(counts, cbase, s0, cursor);
    bucket_scatter_kernel<<<gS1, BLK, 0, stream>>>(h, ccur, staged, N_EDGES);
    final_scatter_kernel<<<NB, BLK, 0, stream>>>(staged, cbase, r, t, cursor, rtp);

    // ---- layer 0 precompute ----
    rel_pre_kernel<<<gRD, BLK, 0, stream>>>(R, DD, Wr0, W0 + DD * DD, 1,
                                            rel0, LD, RW);
    sr_kernel<<<2, BLK, 0, stream>>>(RW, a0, sr);
    ent_pre_v4<3><<<gPRE, BLK, 0, stream>>>(E, DD, W0, W0 + 2 * DD * DD, Wd, bd, a0,
                                            EW1, LD, EW3, LD2, Ed, LD, sh, st);

    // ---- layer 0 attention (fused score+softmax+accumulate) ----
    accum_fused_kernel<<<gW, BLK, 0, stream>>>(s0, counts, rtp, sh, sr, st,
                                               EW1, RW, EW3, nullptr, e0, 1);

    // ---- layer 1 precompute ----
    rel_pre_kernel<<<gRD, BLK, 0, stream>>>(rel0, LD, Wr1, W1 + DD * DD, 0,
                                            out_rel, DD, RW);
    sr_kernel<<<2, BLK, 0, stream>>>(RW, a1, sr);
    ent_pre_v4<2><<<gPRE, BLK, 0, stream>>>(e0, LD, W1, W1 + 2 * DD * DD,
                                            nullptr, nullptr, a1,
                                            EW1, LD, EW3, LD2, nullptr, LD, sh, st);

    // ---- layer 1 attention + fused residual ----
    accum_fused_kernel<<<gW, BLK, 0, stream>>>(s0, counts, rtp, sh, sr, st,
                                               EW1, RW, EW3, Ed, out_ent, 0);
}

// Round 9
// 589.900 us; speedup vs baseline: 5.0634x; 1.0805x over previous
//
#include <hip/hip_runtime.h>

#define N_ENT   100000
#define N_REL   500
#define DD      50
#define LD      52      // fp32 stride for sequentially-read tables (EW1/Ed/e0): 208 B
#define LD2     64      // fp32 stride for RW (L2-resident gather): 256 B
#define LDH     64      // bf16 stride for EW3h: 64 shorts = 128 B = 1 cache line
#define N_EDGES 2000000
#define T_BITS  17
#define T_MASK  0x1FFFF
#define BBITS   9                    // 512 entities per coarse bucket
#define BMASK   511
#define NB      196                  // ceil(N_ENT / 512)
#define CHUNK   8192                 // edges per bucket_scatter block

__device__ inline unsigned int pack_bf2(float x, float y) {
    unsigned int xu = __float_as_uint(x);
    unsigned int yu = __float_as_uint(y);
    xu = (xu + 0x7FFFu + ((xu >> 16) & 1u)) >> 16;   // round-to-nearest-even
    yu = (yu + 0x7FFFu + ((yu >> 16) & 1u)) >> 16;
    return xu | (yu << 16);
}

// ---------------------------------------------------------------------------
// Small GEMM, LDS-staged output + fused row-dot-a:
//   Ya[m][:]  = X@Wa   fp32 stride LD  ; shOut[m] = row.a
//   Ybh[m][:] = X@Wb   bf16 stride LDH ; stOut[m] = row.a (dot from fp32)
//   Yc[m][:]  = X@Wc+bd fp32 stride LD   [NMAT==3 only]
// All fp32 LDS staging at stride 52 (bank-spread); bf16 staging aliased on sX.
// ---------------------------------------------------------------------------
template<int NMAT>
__global__ __launch_bounds__(256) void ent_pre_v5(
    const float* __restrict__ X, int ldX,
    const float* __restrict__ Wa,
    const float* __restrict__ Wb,
    const float* __restrict__ Wc,
    const float* __restrict__ bd,
    const float* __restrict__ avec,
    float* __restrict__ Ya,
    unsigned short* __restrict__ Ybh,
    float* __restrict__ Yc,
    float* __restrict__ shOut,
    float* __restrict__ stOut)
{
    constexpr int MT = 20;       // rows per block; N_ENT % MT == 0
    __shared__ __align__(16) float sW[NMAT][DD * DD];
    __shared__ __align__(16) float sX[MT * 52];   // reused as bf16 staging later
    __shared__ __align__(16) float sY[MT * 52];
    __shared__ float sa[DD];

    const int tid = threadIdx.x;

    for (int i = tid; i < DD * DD / 4; i += 256) {
        ((float4*)sW[0])[i] = ((const float4*)Wa)[i];
        ((float4*)sW[1])[i] = ((const float4*)Wb)[i];
        if (NMAT == 3) ((float4*)sW[2])[i] = ((const float4*)Wc)[i];
    }
    if (tid < DD) sa[tid] = avec[tid];

    const int m0 = blockIdx.x * MT;
    const int nX4 = MT * ldX / 4;
    const float4* xsrc = (const float4*)(X + (size_t)m0 * ldX);
    for (int i = tid; i < nX4; i += 256) ((float4*)sX)[i] = xsrc[i];
    __syncthreads();

    const bool active = (tid < 250);
    const int mp = active ? tid / 25 : 0;
    const int jp = active ? tid % 25 : 0;
    const int r0 = 2 * mp, r1 = 2 * mp + 1, j0 = 2 * jp;

    float acc[NMAT][2][2];
    #pragma unroll
    for (int t = 0; t < NMAT; t++)
        #pragma unroll
        for (int i = 0; i < 2; i++)
            #pragma unroll
            for (int c = 0; c < 2; c++) acc[t][i][c] = 0.f;

    if (active) {
        if (NMAT == 3) {
            float b0 = bd[j0], b1 = bd[j0 + 1];
            acc[2][0][0] = b0; acc[2][0][1] = b1;
            acc[2][1][0] = b0; acc[2][1][1] = b1;
        }
        const float* xr0 = &sX[r0 * ldX];
        const float* xr1 = &sX[r1 * ldX];
        for (int k = 0; k < DD; k++) {
            float x0 = xr0[k], x1 = xr1[k];
            #pragma unroll
            for (int t = 0; t < NMAT; t++) {
                float2 w = *(const float2*)&sW[t][k * DD + j0];
                acc[t][0][0] += x0 * w.x; acc[t][0][1] += x0 * w.y;
                acc[t][1][0] += x1 * w.x; acc[t][1][1] += x1 * w.y;
            }
        }
    }

    // zero fp32 pad cols 50,51 (persist across all t stages)
    if (tid < MT * 2) sY[(tid >> 1) * 52 + 50 + (tid & 1)] = 0.f;

    // ---- stage 0: Ya (fp32, stride LD) + sh dot ----
    if (active) {
        sY[r0 * 52 + j0]     = acc[0][0][0];
        sY[r0 * 52 + j0 + 1] = acc[0][0][1];
        sY[r1 * 52 + j0]     = acc[0][1][0];
        sY[r1 * 52 + j0 + 1] = acc[0][1][1];
    }
    __syncthreads();
    {
        float4* dst = (float4*)(Ya + (size_t)m0 * LD);
        for (int i = tid; i < MT * LD / 4; i += 256) dst[i] = ((const float4*)sY)[i];
        if (tid < MT) {
            const float* row = &sY[tid * 52];
            float d = 0.f;
            for (int k = 0; k < DD; k++) d += row[k] * sa[k];
            shOut[m0 + tid] = d;
        }
    }
    __syncthreads();

    // ---- stage 1: Ybh (bf16, stride LDH) + st dot (from fp32) ----
    unsigned int* sYhU = (unsigned int*)sX;       // sX dead after compute; 20*32 uints
    if (active) {
        sY[r0 * 52 + j0]     = acc[1][0][0];
        sY[r0 * 52 + j0 + 1] = acc[1][0][1];
        sY[r1 * 52 + j0]     = acc[1][1][0];
        sY[r1 * 52 + j0 + 1] = acc[1][1][1];
        sYhU[r0 * 32 + jp] = pack_bf2(acc[1][0][0], acc[1][0][1]);
        sYhU[r1 * 32 + jp] = pack_bf2(acc[1][1][0], acc[1][1][1]);
    }
    if (tid < MT * 7) sYhU[(tid / 7) * 32 + 25 + (tid % 7)] = 0u;  // bf16 pads
    __syncthreads();
    {
        float4* dst = (float4*)(Ybh + (size_t)m0 * LDH);   // 128B rows, 16B aligned
        for (int i = tid; i < MT * LDH * 2 / 16; i += 256) dst[i] = ((const float4*)sYhU)[i];
        if (tid < MT) {
            const float* row = &sY[tid * 52];
            float d = 0.f;
            for (int k = 0; k < DD; k++) d += row[k] * sa[k];
            stOut[m0 + tid] = d;
        }
    }

    // ---- stage 2: Yc (fp32, stride LD)  [NMAT==3] ----
    if (NMAT == 3) {
        __syncthreads();
        if (active) {
            sY[r0 * 52 + j0]     = acc[2][0][0];
            sY[r0 * 52 + j0 + 1] = acc[2][0][1];
            sY[r1 * 52 + j0]     = acc[2][1][0];
            sY[r1 * 52 + j0 + 1] = acc[2][1][1];
        }
        __syncthreads();
        float4* dst = (float4*)(Yc + (size_t)m0 * LD);
        for (int i = tid; i < MT * LD / 4; i += 256) dst[i] = ((const float4*)sY)[i];
    }
}

// rel_out = (relu?) Rin @ Wr (stride ld_rel); RW_out = Rin @ Wmid (fp32 stride LD2)
__global__ void rel_pre_kernel(const float* __restrict__ Rin, int ld_in,
                               const float* __restrict__ Wr,
                               const float* __restrict__ Wmid,
                               int do_relu,
                               float* __restrict__ rel_out, int ld_rel,
                               float* __restrict__ RW_out)
{
    __shared__ float sWr[DD * DD];
    __shared__ float sWm[DD * DD];
    for (int i = threadIdx.x; i < DD * DD; i += blockDim.x) {
        sWr[i] = Wr[i];
        sWm[i] = Wmid[i];
    }
    __syncthreads();
    int idx = blockIdx.x * blockDim.x + threadIdx.x;
    if (idx >= N_REL * DD) return;
    int m = idx / DD, j = idx - m * DD;
    const float* x = Rin + (size_t)m * ld_in;
    float ar = 0.f, am = 0.f;
    for (int k = 0; k < DD; k++) {
        float xv = x[k];
        ar += xv * sWr[k * DD + j];
        am += xv * sWm[k * DD + j];
    }
    if (do_relu) ar = fmaxf(ar, 0.f);
    rel_out[(size_t)m * ld_rel + j] = ar;
    RW_out[(size_t)m * LD2 + j] = am;
    if (j < LD2 - DD) RW_out[(size_t)m * LD2 + DD + j] = 0.f;
}

// sr[m] = RW[m][:50] . a
__global__ void sr_kernel(const float* __restrict__ RW,
                          const float* __restrict__ avec,
                          float* __restrict__ sr)
{
    int m = blockIdx.x * blockDim.x + threadIdx.x;
    if (m >= N_REL) return;
    float d = 0.f;
    for (int k = 0; k < DD; k++) d += RW[(size_t)m * LD2 + k] * avec[k];
    sr[m] = d;
}

// ---------------------------------------------------------------------------
// CSR build, two-level multisplit (line-dense writes)
// ---------------------------------------------------------------------------
__global__ void hist_kernel(const int* __restrict__ h, int* __restrict__ counts, int nE)
{
    int e = blockIdx.x * blockDim.x + threadIdx.x;
    if (e < nE) atomicAdd(&counts[h[e]], 1);
}

__global__ void coarse_kernel(const int* __restrict__ counts,
                              int* __restrict__ cbase,
                              int* __restrict__ ccur)
{
    __shared__ int s[256];
    const int b = threadIdx.x;
    int sum = 0;
    if (b < NB) {
        const int u0 = b << BBITS;
        const int nm = min(512, N_ENT - u0);
        const int4* c4 = (const int4*)(counts + u0);
        for (int k = 0; k < nm / 4; k++) {
            int4 v = c4[k];
            sum += v.x + v.y + v.z + v.w;
        }
    }
    s[b] = sum;
    __syncthreads();
    for (int off = 1; off < 256; off <<= 1) {
        int v = (b >= off) ? s[b - off] : 0;
        __syncthreads();
        s[b] += v;
        __syncthreads();
    }
    if (b < NB) {
        int excl = s[b] - sum;
        cbase[b] = excl;
        ccur[b] = excl;
    }
    if (b == NB - 1) cbase[NB] = s[b];
}

__global__ void assign2_kernel(const int* __restrict__ counts,
                               const int* __restrict__ cbase,
                               int* __restrict__ s0,
                               int* __restrict__ cursor)
{
    const int w = (blockIdx.x * blockDim.x + threadIdx.x) >> 6;
    if (w >= NB) return;
    const int lane = threadIdx.x & 63;
    const int u0 = (w << BBITS) + lane * 8;
    int pre[8];
    int s = 0;
    #pragma unroll
    for (int k = 0; k < 8; k++) {
        int u = u0 + k;
        int c = (u < N_ENT) ? counts[u] : 0;
        pre[k] = s;
        s += c;
    }
    int incl = s;
    #pragma unroll
    for (int off = 1; off < 64; off <<= 1) {
        int v = __shfl_up(incl, off);
        if (lane >= off) incl += v;
    }
    const int base = cbase[w] + incl - s;
    #pragma unroll
    for (int k = 0; k < 8; k++) {
        int u = u0 + k;
        if (u < N_ENT) {
            s0[u] = base + pre[k];
            cursor[u] = base + pre[k];
        }
    }
}

// S1: LDS multisplit into NB staged bucket regions. word = (e<<9)|(h&511)
__global__ __launch_bounds__(256) void bucket_scatter_kernel(
    const int* __restrict__ h,
    int* __restrict__ ccur,
    unsigned int* __restrict__ staged, int nE)
{
    __shared__ int sHist[NB];
    __shared__ int sScan[256];
    __shared__ int sBase[NB];
    __shared__ int sCur[NB];
    __shared__ int sGb[NB];
    __shared__ unsigned int sBuf[CHUNK];
    __shared__ unsigned char sBkt[CHUNK];

    const int tid = threadIdx.x;
    const int e0 = blockIdx.x * CHUNK;
    const int n = min(CHUNK, nE - e0);

    for (int i = tid; i < NB; i += 256) sHist[i] = 0;
    __syncthreads();

    #pragma unroll
    for (int k = 0; k < CHUNK / 256; k++) {
        int e = e0 + k * 256 + tid;
        if (e < nE) atomicAdd(&sHist[h[e] >> BBITS], 1);
    }
    __syncthreads();

    int v = (tid < NB) ? sHist[tid] : 0;
    sScan[tid] = v;
    __syncthreads();
    for (int off = 1; off < 256; off <<= 1) {
        int x = (tid >= off) ? sScan[tid - off] : 0;
        __syncthreads();
        sScan[tid] += x;
        __syncthreads();
    }
    if (tid < NB) {
        int excl = sScan[tid] - v;
        sBase[tid] = excl;
        sCur[tid] = excl;
    }
    __syncthreads();

    #pragma unroll
    for (int k = 0; k < CHUNK / 256; k++) {
        int e = e0 + k * 256 + tid;
        if (e < nE) {
            int hv = h[e];
            int b = hv >> BBITS;
            int pos = atomicAdd(&sCur[b], 1);
            sBuf[pos] = ((unsigned int)e << BBITS) | (unsigned int)(hv & BMASK);
            sBkt[pos] = (unsigned char)b;
        }
    }
    __syncthreads();

    if (tid < NB) {
        int cnt = sHist[tid];
        sGb[tid] = cnt ? atomicAdd(&ccur[tid], cnt) : 0;
    }
    __syncthreads();

    for (int i = tid; i < n; i += 256) {
        int b = sBkt[i];
        staged[sGb[b] + (i - sBase[b])] = sBuf[i];
    }
}

// S2: one block per bucket; exact placement into contiguous rtp window
__global__ void final_scatter_kernel(const unsigned int* __restrict__ staged,
                                     const int* __restrict__ cbase,
                                     const int* __restrict__ r,
                                     const int* __restrict__ t,
                                     int* __restrict__ cursor,
                                     unsigned int* __restrict__ rtp)
{
    const int b = blockIdx.x;
    const int i0 = cbase[b], i1 = cbase[b + 1];
    for (int i = i0 + threadIdx.x; i < i1; i += 256) {
        unsigned int w = staged[i];
        int e = w >> BBITS;
        int u = (b << BBITS) | (int)(w & BMASK);
        int pos = atomicAdd(&cursor[u], 1);
        rtp[pos] = ((unsigned int)r[e] << T_BITS) | (unsigned int)t[e];
    }
}

// ---------------------------------------------------------------------------
// Fused score + accumulate, one WAVE per head. EW3 gathered as bf16 (1 line).
// ---------------------------------------------------------------------------
__global__ __launch_bounds__(256) void accum_fused_kernel(
    const int* __restrict__ s0v,
    const int* __restrict__ counts,
    const unsigned int* __restrict__ rtp,
    const float* __restrict__ sh,
    const float* __restrict__ sr,
    const float* __restrict__ st,
    const float* __restrict__ EW1,
    const float* __restrict__ RW,
    const unsigned short* __restrict__ EW3h,
    const float* __restrict__ base,
    float* __restrict__ outp, int full_ld)
{
    const int u = (blockIdx.x * blockDim.x + threadIdx.x) >> 6;  // wave id
    if (u >= N_ENT) return;
    const int lane = threadIdx.x & 63;
    const int eg = lane / 13;          // 0..4 (eg==4 -> lanes 52..63 idle)
    const int q  = lane - eg * 13;

    const int b = s0v[u];
    const int c = counts[u];
    const float shu = sh[u];

    float4 acc = make_float4(0.f, 0.f, 0.f, 0.f);
    float asum = 0.f;

    if (eg < 4) {
        for (int i = eg; i < c; i += 4) {
            unsigned int w = rtp[b + i];
            int rr = w >> T_BITS;
            int tt = w & T_MASK;
            float sc = shu + sr[rr] + st[tt];
            sc = sc >= 0.f ? sc : 0.2f * sc;
            float ex = __expf(sc);
            float4 vr = *(const float4*)(RW + (size_t)rr * LD2 + 4 * q);
            uint2 th = *(const uint2*)(EW3h + (size_t)tt * LDH + 4 * q);
            float t0 = __uint_as_float(th.x << 16);
            float t1 = __uint_as_float(th.x & 0xFFFF0000u);
            float t2 = __uint_as_float(th.y << 16);
            float t3 = __uint_as_float(th.y & 0xFFFF0000u);
            asum += ex;
            acc.x += ex * (vr.x + t0);
            acc.y += ex * (vr.y + t1);
            acc.z += ex * (vr.z + t2);
            acc.w += ex * (vr.w + t3);
        }
    }

    acc.x += __shfl_down(acc.x, 26); acc.y += __shfl_down(acc.y, 26);
    acc.z += __shfl_down(acc.z, 26); acc.w += __shfl_down(acc.w, 26);
    asum  += __shfl_down(asum, 26);
    acc.x += __shfl_down(acc.x, 13); acc.y += __shfl_down(acc.y, 13);
    acc.z += __shfl_down(acc.z, 13); acc.w += __shfl_down(acc.w, 13);
    asum  += __shfl_down(asum, 13);

    if (lane >= 13) return;

    if (asum > 0.f) {
        float inv = 1.f / asum;
        float4 w1 = *(const float4*)(EW1 + (size_t)u * LD + 4 * lane);
        acc.x = w1.x + acc.x * inv;
        acc.y = w1.y + acc.y * inv;
        acc.z = w1.z + acc.z * inv;
        acc.w = w1.w + acc.w * inv;
    }
    if (base) {
        float4 bb = *(const float4*)(base + (size_t)u * LD + 4 * lane);
        acc.x += bb.x; acc.y += bb.y; acc.z += bb.z; acc.w += bb.w;
    }
    if (full_ld) {
        *(float4*)(outp + (size_t)u * LD + 4 * lane) = acc;
    } else {
        int j0 = 4 * lane;
        float v[4] = { acc.x, acc.y, acc.z, acc.w };
        #pragma unroll
        for (int cc = 0; cc < 4; cc++)
            if (j0 + cc < DD) outp[(size_t)u * DD + j0 + cc] = v[cc];
    }
}

// ---------------------------------------------------------------------------
extern "C" void kernel_launch(void* const* d_in, const int* in_sizes, int n_in,
                              void* d_out, int out_size, void* d_ws, size_t ws_size,
                              hipStream_t stream)
{
    const int*   h   = (const int*)d_in[0];
    const int*   r   = (const int*)d_in[1];
    const int*   t   = (const int*)d_in[2];
    const float* E   = (const float*)d_in[3];
    const float* R   = (const float*)d_in[4];
    const float* W0  = (const float*)d_in[5];
    const float* a0  = (const float*)d_in[6];
    const float* Wr0 = (const float*)d_in[7];
    const float* W1  = (const float*)d_in[8];
    const float* a1  = (const float*)d_in[9];
    const float* Wr1 = (const float*)d_in[10];
    const float* Wd  = (const float*)d_in[11];
    const float* bd  = (const float*)d_in[12];

    float* out_ent = (float*)d_out;                 // [N_ENT, DD] stride DD
    float* out_rel = out_ent + (size_t)N_ENT * DD;  // [N_REL, DD] stride DD

    // workspace layout (~94 MB)
    float* ws_f  = (float*)d_ws;
    float* EW1   = ws_f;                                   // N_ENT*LD
    float* Ed    = EW1  + (size_t)N_ENT * LD;              // N_ENT*LD
    float* e0    = Ed   + (size_t)N_ENT * LD;              // N_ENT*LD
    unsigned short* EW3h = (unsigned short*)(e0 + (size_t)N_ENT * LD);  // N_ENT*LDH bf16
    float* RW    = (float*)(EW3h + (size_t)N_ENT * LDH);   // N_REL*LD2
    float* rel0  = RW   + (size_t)N_REL * LD2;             // N_REL*LD
    float* sh    = rel0 + (size_t)N_REL * LD;              // N_ENT
    float* st    = sh   + N_ENT;                           // N_ENT
    float* sr    = st   + N_ENT;                           // N_REL
    int* counts  = (int*)(sr + N_REL);                     // N_ENT
    int* s0      = counts + N_ENT;                         // N_ENT
    int* cursor  = s0 + N_ENT;                             // N_ENT
    int* cbase   = cursor + N_ENT;                         // NB+1
    int* ccur    = cbase + NB + 1;                         // NB
    unsigned int* rtp    = (unsigned int*)(ccur + NB);     // N_EDGES
    unsigned int* staged = rtp + N_EDGES;                  // N_EDGES

    const int BLK = 256;
    const int gE   = (N_EDGES + BLK - 1) / BLK;
    const int gW   = (N_ENT + 3) / 4;            // accum: 1 wave/head
    const int gRD  = (N_REL * DD + BLK - 1) / BLK;
    const int gPRE = N_ENT / 20;
    const int gS1  = (N_EDGES + CHUNK - 1) / CHUNK;
    const int gA2  = (NB + 3) / 4;

    // ---- CSR build (two-level multisplit; shared by both layers) ----
    hipMemsetAsync(counts, 0, (size_t)N_ENT * sizeof(int), stream);
    hist_kernel<<<gE, BLK, 0, stream>>>(h, counts, N_EDGES);
    coarse_kernel<<<1, 256, 0, stream>>>(counts, cbase, ccur);
    assign2_kernel<<<gA2, BLK, 0, stream>>>(counts, cbase, s0, cursor);
    bucket_scatter_kernel<<<gS1, BLK, 0, stream>>>(h, ccur, staged, N_EDGES);
    final_scatter_kernel<<<NB, BLK, 0, stream>>>(staged, cbase, r, t, cursor, rtp);

    // ---- layer 0 precompute ----
    rel_pre_kernel<<<gRD, BLK, 0, stream>>>(R, DD, Wr0, W0 + DD * DD, 1,
                                            rel0, LD, RW);
    sr_kernel<<<2, BLK, 0, stream>>>(RW, a0, sr);
    ent_pre_v5<3><<<gPRE, BLK, 0, stream>>>(E, DD, W0, W0 + 2 * DD * DD, Wd, bd, a0,
                                            EW1, EW3h, Ed, sh, st);

    // ---- layer 0 attention (fused score+softmax+accumulate) ----
    accum_fused_kernel<<<gW, BLK, 0, stream>>>(s0, counts, rtp, sh, sr, st,
                                               EW1, RW, EW3h, nullptr, e0, 1);

    // ---- layer 1 precompute ----
    rel_pre_kernel<<<gRD, BLK, 0, stream>>>(rel0, LD, Wr1, W1 + DD * DD, 0,
                                            out_rel, DD, RW);
    sr_kernel<<<2, BLK, 0, stream>>>(RW, a1, sr);
    ent_pre_v5<2><<<gPRE, BLK, 0, stream>>>(e0, LD, W1, W1 + 2 * DD * DD,
                                            nullptr, nullptr, a1,
                                            EW1, EW3h, nullptr, sh, st);

    // ---- layer 1 attention + fused residual ----
    accum_fused_kernel<<<gW, BLK, 0, stream>>>(s0, counts, rtp, sh, sr, st,
                                               EW1, RW, EW3h, Ed, out_ent, 0);
}